// Round 3
// baseline (6086.509 us; speedup 1.0000x reference)
//
#include <hip/hip_runtime.h>

#define KCODES 4096
#define DIM    256
#define NROWS  65536
#define BM     64
#define BN     64
#define LSTRIDE (DIM + 4)   // float units; keeps 16B alignment, spreads LDS banks

// ---- numpy-faithful pairwise sum of squares of 128 consecutive floats ----
// numpy pairwise_sum, n=128 path: r[j] = sum_i a[8i+j] (sequential in i),
// combine ((r0+r1)+(r2+r3))+((r4+r5)+(r6+r7)). Squares rounded to f32 first
// (np computes the z**2 temp array, then sums it).
__device__ __forceinline__ float np_half_sum128(const float4* __restrict__ p4) {
    #pragma clang fp contract(off)
    float4 v0 = p4[0], v1 = p4[1];
    float r0 = v0.x * v0.x, r1 = v0.y * v0.y, r2 = v0.z * v0.z, r3 = v0.w * v0.w;
    float r4 = v1.x * v1.x, r5 = v1.y * v1.y, r6 = v1.z * v1.z, r7 = v1.w * v1.w;
    #pragma unroll
    for (int i = 1; i < 16; ++i) {
        float4 a = p4[2 * i], b = p4[2 * i + 1];
        r0 += a.x * a.x; r1 += a.y * a.y; r2 += a.z * a.z; r3 += a.w * a.w;
        r4 += b.x * b.x; r5 += b.y * b.y; r6 += b.z * b.z; r7 += b.w * b.w;
    }
    return ((r0 + r1) + (r2 + r3)) + ((r4 + r5) + (r6 + r7));
}

// row norm with exact numpy f32 semantics: n=256 splits into 128+128
__global__ void k_rownorm(const float* __restrict__ src, float* __restrict__ dst, int nrows) {
    int r = blockIdx.x * blockDim.x + threadIdx.x;
    if (r >= nrows) return;
    const float4* p4 = (const float4*)(src + (size_t)r * DIM);
    float s;
    {
        #pragma clang fp contract(off)
        s = np_half_sum128(p4) + np_half_sum128(p4 + 32);
    }
    dst[r] = s;
}

// d = fl32( fl32(Cr + ebc) - fl32(2 * fl32(cross)) ), contraction disabled so
// every rounding matches numpy's broadcast-add / scalar-mul / subtract chain.
__device__ __forceinline__ float f32_dist(float Cr, float ebc, double accv) {
    #pragma clang fp contract(off)
    float A = Cr + ebc;
    float B = 2.0f * (float)accv;   // (float)acc == correctly-rounded f32 cross
    return A - B;
}

// ---------------- main: f64 cross + f32-faithful distance + argmin ----------------
__global__ __launch_bounds__(256, 1)
void k_main(const float* __restrict__ z, const float* __restrict__ e,
            const float* __restrict__ Crow, const float* __restrict__ eb2,
            float* __restrict__ out, double* __restrict__ partial) {
    __shared__ float  zt[BM][LSTRIDE];
    __shared__ float  et[BN][LSTRIDE];
    __shared__ float  redd[BM][17];
    __shared__ int    redi[BM][17];
    __shared__ int    bsel[BM];
    __shared__ double lred[4];

    const int t  = threadIdx.x;
    const int tx = t & 15;        // code group
    const int ty = t >> 4;        // row group (0..15), 4 rows each
    const int row0 = blockIdx.x * BM;

    // ---- stage z tile (64 rows x 256) as float4, coalesced ----
    {
        const float4* zsrc = (const float4*)(z + (size_t)row0 * DIM);
        for (int i = t; i < BM * (DIM / 4); i += 256) {
            int r = i >> 6, c4 = i & 63;
            float4 v = zsrc[r * (DIM / 4) + c4];
            *(float4*)&zt[r][c4 * 4] = v;
        }
    }

    float Cr[4];
    #pragma unroll
    for (int ri = 0; ri < 4; ++ri) Cr[ri] = Crow[row0 + ty * 4 + ri];

    float bestd[4];
    int   besti[4];
    #pragma unroll
    for (int ri = 0; ri < 4; ++ri) { bestd[ri] = __int_as_float(0x7f800000); besti[ri] = 0; }

    for (int kt = 0; kt < KCODES / BN; ++kt) {
        __syncthreads();
        {
            const float4* esrc = (const float4*)(e + (size_t)kt * BN * DIM);
            for (int i = t; i < BN * (DIM / 4); i += 256) {
                int r = i >> 6, c4 = i & 63;
                float4 v = esrc[r * (DIM / 4) + c4];
                *(float4*)&et[r][c4 * 4] = v;
            }
        }
        __syncthreads();

        double acc[4][4];
        #pragma unroll
        for (int a = 0; a < 4; ++a)
            #pragma unroll
            for (int b = 0; b < 4; ++b) acc[a][b] = 0.0;

        #pragma unroll 4
        for (int d4 = 0; d4 < DIM / 4; ++d4) {
            float4 za[4], ea[4];
            #pragma unroll
            for (int ri = 0; ri < 4; ++ri) za[ri] = *(const float4*)&zt[ty * 4 + ri][d4 * 4];
            #pragma unroll
            for (int ci = 0; ci < 4; ++ci) ea[ci] = *(const float4*)&et[tx + 16 * ci][d4 * 4];
            #pragma unroll
            for (int ri = 0; ri < 4; ++ri)
                #pragma unroll
                for (int ci = 0; ci < 4; ++ci) {
                    acc[ri][ci] += (double)za[ri].x * (double)ea[ci].x
                                 + (double)za[ri].y * (double)ea[ci].y
                                 + (double)za[ri].z * (double)ea[ci].z
                                 + (double)za[ri].w * (double)ea[ci].w;
                }
        }

        // argmin update in f32-reference semantics.
        // scan order (kt asc, ci asc) => candidate index strictly increasing,
        // strict < keeps the first (= numpy argmin tie-break within thread).
        #pragma unroll
        for (int ci = 0; ci < 4; ++ci) {
            int c = kt * BN + tx + 16 * ci;
            float ebc = eb2[c];
            #pragma unroll
            for (int ri = 0; ri < 4; ++ri) {
                float d = f32_dist(Cr[ri], ebc, acc[ri][ci]);
                if (d < bestd[ri]) { bestd[ri] = d; besti[ri] = c; }
            }
        }
    }

    // ---- cross-thread argmin reduction, lexicographic (d, idx) ----
    __syncthreads();
    #pragma unroll
    for (int ri = 0; ri < 4; ++ri) {
        redd[ty * 4 + ri][tx] = bestd[ri];
        redi[ty * 4 + ri][tx] = besti[ri];
    }
    __syncthreads();
    if (t < BM) {
        float bd = redd[t][0];
        int   bi = redi[t][0];
        for (int j = 1; j < 16; ++j) {
            float d  = redd[t][j];
            int   i2 = redi[t][j];
            if (d < bd || (d == bd && i2 < bi)) { bd = d; bi = i2; }
        }
        bsel[t] = bi;
        out[1 + (size_t)NROWS * DIM + row0 + t] = (float)bi;
    }
    __syncthreads();

    // ---- gather quantized rows + loss partial ----
    double lacc = 0.0;
    {
        int r  = t >> 2;
        int qd = (t & 3) * 64;
        int bi = bsel[r];
        const float* qrow = e + (size_t)bi * DIM + qd;
        float*       orow = out + 1 + (size_t)(row0 + r) * DIM + qd;
        #pragma unroll 4
        for (int d = 0; d < 64; ++d) {
            float qv = qrow[d];
            float zv = zt[r][qd + d];
            double df = (double)qv - (double)zv;
            lacc += df * df;
            orow[d] = qv;
        }
    }
    for (int off = 32; off > 0; off >>= 1) lacc += __shfl_down(lacc, off, 64);
    if ((t & 63) == 0) lred[t >> 6] = lacc;
    __syncthreads();
    if (t == 0) partial[blockIdx.x] = lred[0] + lred[1] + lred[2] + lred[3];
}

// ---------------- deterministic finish for loss ----------------
__global__ void k_finish(const double* __restrict__ partial, float* __restrict__ out) {
    __shared__ double s[256];
    double a = 0.0;
    for (int i = threadIdx.x; i < NROWS / BM; i += 256) a += partial[i];
    s[threadIdx.x] = a;
    __syncthreads();
    for (int off = 128; off > 0; off >>= 1) {
        if (threadIdx.x < off) s[threadIdx.x] += s[threadIdx.x + off];
        __syncthreads();
    }
    if (threadIdx.x == 0)
        out[0] = (float)(1.25 * s[0] / ((double)NROWS * (double)DIM));
}

extern "C" void kernel_launch(void* const* d_in, const int* in_sizes, int n_in,
                              void* d_out, int out_size, void* d_ws, size_t ws_size,
                              hipStream_t stream) {
    const float* z = (const float*)d_in[0];   // [65536, 256]
    const float* e = (const float*)d_in[1];   // [4096, 256]
    float* out = (float*)d_out;               // [1 + 65536*256 + 65536]

    float*  Crow    = (float*)d_ws;           // 65536 f32  (|z_n|^2, np-faithful)
    float*  eb2     = Crow + NROWS;           // 4096 f32   (|e_k|^2, np-faithful)
    double* partial = (double*)(eb2 + KCODES);// 1024 f64 (8-aligned: 278528 bytes)

    k_rownorm<<<NROWS / 256, 256, 0, stream>>>(z, Crow, NROWS);
    k_rownorm<<<KCODES / 256, 256, 0, stream>>>(e, eb2, KCODES);
    k_main<<<NROWS / BM, 256, 0, stream>>>(z, e, Crow, eb2, out, partial);
    k_finish<<<1, 256, 0, stream>>>(partial, out);
}

// Round 4
// 1218.044 us; speedup vs baseline: 4.9970x; 4.9970x over previous
//
#include <hip/hip_runtime.h>

#define KCODES 4096
#define DIM    256
#define NROWS  65536
#define MARGIN 4.0e-4f
#define LSTRIDE (DIM + 4)

typedef unsigned long long u64;
typedef unsigned int  uint;
typedef unsigned short ushort;
typedef __attribute__((ext_vector_type(8))) short bf16x8;
typedef __attribute__((ext_vector_type(4))) float f32x4;

// ============================ shared helpers ============================

// numpy-faithful pairwise sum of squares of 128 consecutive floats
__device__ __forceinline__ float np_half_sum128(const float4* __restrict__ p4) {
    #pragma clang fp contract(off)
    float4 v0 = p4[0], v1 = p4[1];
    float r0 = v0.x * v0.x, r1 = v0.y * v0.y, r2 = v0.z * v0.z, r3 = v0.w * v0.w;
    float r4 = v1.x * v1.x, r5 = v1.y * v1.y, r6 = v1.z * v1.z, r7 = v1.w * v1.w;
    #pragma unroll
    for (int i = 1; i < 16; ++i) {
        float4 a = p4[2 * i], b = p4[2 * i + 1];
        r0 += a.x * a.x; r1 += a.y * a.y; r2 += a.z * a.z; r3 += a.w * a.w;
        r4 += b.x * b.x; r5 += b.y * b.y; r6 += b.z * b.z; r7 += b.w * b.w;
    }
    return ((r0 + r1) + (r2 + r3)) + ((r4 + r5) + (r6 + r7));
}

__global__ void k_rownorm(const float* __restrict__ src, float* __restrict__ dst, int nrows) {
    int r = blockIdx.x * blockDim.x + threadIdx.x;
    if (r >= nrows) return;
    const float4* p4 = (const float4*)(src + (size_t)r * DIM);
    float s;
    {
        #pragma clang fp contract(off)
        s = np_half_sum128(p4) + np_half_sum128(p4 + 32);
    }
    dst[r] = s;
}

// d = fl32( fl32(Cr + ebc) - fl32(2 * fl32(cross_exact)) )  -- validated (round 3)
__device__ __forceinline__ float f32_dist(float Cr, float ebc, double accv) {
    #pragma clang fp contract(off)
    float A = Cr + ebc;
    float B = 2.0f * (float)accv;
    return A - B;
}

__device__ __forceinline__ ushort f2bf(float f) {  // RNE f32->bf16
    uint u = __float_as_uint(f);
    return (ushort)((u + 0x7fffu + ((u >> 16) & 1u)) >> 16);
}

// ============================ fast-path kernels ============================

__global__ void k_split(const float* __restrict__ src, ushort* __restrict__ dst, int n8) {
    int i = blockIdx.x * blockDim.x + threadIdx.x;
    if (i >= n8) return;
    const float4* s4 = (const float4*)src;
    float4 a = s4[2 * i], b = s4[2 * i + 1];
    uint4 ov;
    ov.x = (uint)f2bf(a.x) | ((uint)f2bf(a.y) << 16);
    ov.y = (uint)f2bf(a.z) | ((uint)f2bf(a.w) << 16);
    ov.z = (uint)f2bf(b.x) | ((uint)f2bf(b.y) << 16);
    ov.w = (uint)f2bf(b.z) | ((uint)f2bf(b.w) << 16);
    *(uint4*)&dst[8 * i] = ov;
}

__global__ void k_init(u64* __restrict__ fkey, int* __restrict__ cnt) {
    int i = blockIdx.x * 256 + threadIdx.x;
    fkey[i] = ~0ull;
    if (i < 32) cnt[i] = 0;
}

// MFMA filter GEMM: per (128-row, 128-code) block, min packed key per row-tile.
// A = z_hi [65536x256 bf16], B^T = e_hi [4096x256 bf16]; K=256, BK=64, dbuf.
__global__ __launch_bounds__(256, 2)
void k_gemm(const ushort* __restrict__ zh, const ushort* __restrict__ eh,
            const float* __restrict__ Crow, const float* __restrict__ eb2,
            u64* __restrict__ tkeys) {
    __shared__ __align__(16) ushort As[2][128 * 64];
    __shared__ __align__(16) ushort Bs[2][128 * 64];

    const int t = threadIdx.x;
    const int lane = t & 63;
    const int wv = t >> 6;       // wave 0..3
    const int wm = wv >> 1;      // row half
    const int wn = wv & 1;       // col half
    const int bid = blockIdx.x;
    const int ct = bid & 31, rt = bid >> 5;
    const int row0 = rt * 128, col0 = ct * 128;
    const int l15 = lane & 15, l4 = lane >> 4;

    f32x4 acc[4][4];
    #pragma unroll
    for (int i = 0; i < 4; ++i)
        #pragma unroll
        for (int j = 0; j < 4; ++j) acc[i][j] = (f32x4){0.f, 0.f, 0.f, 0.f};

    const uint4* zg = (const uint4*)zh;   // 8 bf16 per uint4
    const uint4* eg = (const uint4*)eh;
    uint4 ra[4], rb[4];

    auto gload = [&](int kt) {
        #pragma unroll
        for (int i = 0; i < 4; ++i) {
            int u = t + 256 * i; int r = u >> 3, c = u & 7;
            ra[i] = zg[(size_t)(row0 + r) * 32 + kt * 8 + c];
            rb[i] = eg[(size_t)(col0 + r) * 32 + kt * 8 + c];
        }
    };
    auto sstore = [&](int buf) {
        #pragma unroll
        for (int i = 0; i < 4; ++i) {
            int u = t + 256 * i; int r = u >> 3, c = u & 7;
            int sc = c ^ (r & 7);                       // XOR swizzle (G4/T2)
            *(uint4*)&As[buf][r * 64 + sc * 8] = ra[i];
            *(uint4*)&Bs[buf][r * 64 + sc * 8] = rb[i];
        }
    };

    gload(0);
    sstore(0);
    __syncthreads();

    for (int kt = 0; kt < 4; ++kt) {
        int buf = kt & 1;
        if (kt < 3) gload(kt + 1);
        bf16x8 af[2][4], bfv[2][4];
        #pragma unroll
        for (int ks = 0; ks < 2; ++ks) {
            #pragma unroll
            for (int mi = 0; mi < 4; ++mi) {
                int rA = wm * 64 + mi * 16 + l15;
                int kc = (ks * 4 + l4) ^ (rA & 7);
                af[ks][mi] = *(const bf16x8*)&As[buf][rA * 64 + kc * 8];
            }
            #pragma unroll
            for (int ni = 0; ni < 4; ++ni) {
                int rB = wn * 64 + ni * 16 + l15;
                int kc = (ks * 4 + l4) ^ (rB & 7);
                bfv[ks][ni] = *(const bf16x8*)&Bs[buf][rB * 64 + kc * 8];
            }
        }
        #pragma unroll
        for (int ks = 0; ks < 2; ++ks)
            #pragma unroll
            for (int mi = 0; mi < 4; ++mi)
                #pragma unroll
                for (int ni = 0; ni < 4; ++ni)
                    acc[mi][ni] = __builtin_amdgcn_mfma_f32_16x16x32_bf16(
                        af[ks][mi], bfv[ks][ni], acc[mi][ni], 0, 0, 0);
        if (kt < 3) sstore((kt + 1) & 1);
        __syncthreads();
    }

    // epilogue: d = (Crow+eb2) - 2*cross; per-row min of packed (d,idx) key.
    // D-frag mapping (m89): col = lane&15, row = (lane>>4)*4 + reg.
    u64* red = (u64*)As;   // [128][2], safe after final barrier
    float eb[4];
    #pragma unroll
    for (int ni = 0; ni < 4; ++ni) eb[ni] = eb2[col0 + wn * 64 + ni * 16 + l15];

    #pragma unroll
    for (int mi = 0; mi < 4; ++mi) {
        #pragma unroll
        for (int rg = 0; rg < 4; ++rg) {
            int rloc = wm * 64 + mi * 16 + l4 * 4 + rg;
            float Cr = Crow[row0 + rloc];
            u64 k1 = ~0ull;
            #pragma unroll
            for (int ni = 0; ni < 4; ++ni) {
                float d;
                {
                    #pragma clang fp contract(off)
                    float A = Cr + eb[ni];
                    d = A - 2.0f * acc[mi][ni][rg];
                }
                int cg = col0 + wn * 64 + ni * 16 + l15;
                u64 key = ((u64)__float_as_uint(d) << 32) | (u64)cg;
                k1 = key < k1 ? key : k1;
            }
            #pragma unroll
            for (int m = 1; m <= 8; m <<= 1) {
                u64 o = __shfl_xor(k1, m, 64);
                k1 = o < k1 ? o : k1;
            }
            if (l15 == 0) red[rloc * 2 + wn] = k1;
        }
    }
    __syncthreads();
    if (t < 128) {
        u64 a = red[t * 2], b = red[t * 2 + 1];
        tkeys[(size_t)ct * NROWS + row0 + t] = a < b ? a : b;
    }
}

// per row: rowbest over 32 tiles; append row to each tile within MARGIN
__global__ void k_lists(const u64* __restrict__ tkeys, int* __restrict__ cnt,
                        int* __restrict__ list) {
    int row = blockIdx.x * 256 + threadIdx.x;
    u64 best = ~0ull;
    for (int tt = 0; tt < 32; ++tt) {
        u64 k = tkeys[(size_t)tt * NROWS + row];
        best = k < best ? k : best;
    }
    float cutoff = __uint_as_float((uint)(best >> 32)) + MARGIN;
    for (int tt = 0; tt < 32; ++tt) {
        float v = __uint_as_float((uint)(tkeys[(size_t)tt * NROWS + row] >> 32));
        if (v <= cutoff) {
            int p = atomicAdd(&cnt[tt], 1);
            list[tt * NROWS + p] = row;
        }
    }
}

// exact decider: validated f64-cross + f32_dist + lexicographic key, atomicMin-merged
__global__ __launch_bounds__(256)
void k_exact(const float* __restrict__ z, const float* __restrict__ e,
             const float* __restrict__ Crow, const float* __restrict__ eb2,
             const int* __restrict__ list, const int* __restrict__ cnt,
             u64* __restrict__ fkey) {
    __shared__ __align__(16) float zx[16][260];
    __shared__ __align__(16) float ex[32][260];
    __shared__ int rows[16];
    const int tile = blockIdx.x;
    const int nct = cnt[tile];
    const int t = threadIdx.x;
    const int rl = t & 15;
    const int cs = t >> 4;

    for (int chunk = blockIdx.y; chunk * 16 < nct; chunk += gridDim.y) {
        int base = chunk * 16;
        int nr = nct - base; if (nr > 16) nr = 16;
        __syncthreads();
        if (t < 16) rows[t] = list[tile * NROWS + base + (t < nr ? t : 0)];
        __syncthreads();
        {   // stage z rows (16 x 256 f32)
            int rr = t >> 4, c = t & 15;
            const float4* src = (const float4*)(z + (size_t)rows[rr] * DIM);
            float4* dstrow = (float4*)zx[rr];
            #pragma unroll
            for (int j = 0; j < 4; ++j) dstrow[c + 16 * j] = src[c + 16 * j];
        }
        u64 kbest = ~0ull;
        int myrow = rows[rl];
        float Cr = Crow[myrow];
        for (int s = 0; s < 4; ++s) {
            __syncthreads();
            {   // stage 32 code rows (32 x 256 f32)
                int cc = t >> 3, c8 = t & 7;
                int code = tile * 128 + s * 32 + cc;
                const float4* src = (const float4*)(e + (size_t)code * DIM);
                float4* dstrow = (float4*)ex[cc];
                #pragma unroll
                for (int j = 0; j < 8; ++j) dstrow[c8 + 8 * j] = src[c8 + 8 * j];
            }
            __syncthreads();
            #pragma unroll
            for (int cj = 0; cj < 2; ++cj) {
                int cl = cs + 16 * cj;
                int cglob = tile * 128 + s * 32 + cl;
                double a = 0.0;
                const float4* za  = (const float4*)zx[rl];
                const float4* eb_ = (const float4*)ex[cl];
                #pragma unroll 8
                for (int d4 = 0; d4 < 64; ++d4) {
                    float4 x = za[d4], y = eb_[d4];
                    a += (double)x.x * (double)y.x;
                    a += (double)x.y * (double)y.y;
                    a += (double)x.z * (double)y.z;
                    a += (double)x.w * (double)y.w;
                }
                float d = f32_dist(Cr, eb2[cglob], a);
                u64 key = ((u64)__float_as_uint(d) << 32) | (u64)cglob;
                kbest = key < kbest ? key : kbest;
            }
        }
        atomicMin((unsigned long long*)&fkey[myrow], kbest);
    }
}

// gather quantized + indices + loss partials
__global__ __launch_bounds__(256)
void k_gather(const float* __restrict__ z, const float* __restrict__ e,
              const u64* __restrict__ fkey, float* __restrict__ out,
              double* __restrict__ partial) {
    __shared__ double lred[4];
    const int t = threadIdx.x;
    const int row = blockIdx.x * 32 + (t >> 3);
    const int c8 = t & 7;
    const int idx = (int)(fkey[row] & 0xffffffffull);
    if (c8 == 0) out[1 + (size_t)NROWS * DIM + row] = (float)idx;
    const float4* zr = (const float4*)(z + (size_t)row * DIM);
    const float4* er = (const float4*)(e + (size_t)idx * DIM);
    float4* orow = (float4*)(out + 1 + (size_t)row * DIM);
    double lacc = 0.0;
    #pragma unroll
    for (int j = 0; j < 8; ++j) {
        float4 q = er[c8 + 8 * j];
        float4 zv = zr[c8 + 8 * j];
        orow[c8 + 8 * j] = q;
        double d0 = (double)q.x - (double)zv.x;
        double d1 = (double)q.y - (double)zv.y;
        double d2 = (double)q.z - (double)zv.z;
        double d3 = (double)q.w - (double)zv.w;
        lacc += d0 * d0 + d1 * d1 + d2 * d2 + d3 * d3;
    }
    for (int off = 32; off > 0; off >>= 1) lacc += __shfl_down(lacc, off, 64);
    if ((t & 63) == 0) lred[t >> 6] = lacc;
    __syncthreads();
    if (t == 0) partial[blockIdx.x] = lred[0] + lred[1] + lred[2] + lred[3];
}

__global__ void k_finish(const double* __restrict__ partial, float* __restrict__ out, int n) {
    __shared__ double s[256];
    double a = 0.0;
    for (int i = threadIdx.x; i < n; i += 256) a += partial[i];
    s[threadIdx.x] = a;
    __syncthreads();
    for (int off = 128; off > 0; off >>= 1) {
        if (threadIdx.x < off) s[threadIdx.x] += s[threadIdx.x + off];
        __syncthreads();
    }
    if (threadIdx.x == 0)
        out[0] = (float)(1.25 * s[0] / ((double)NROWS * (double)DIM));
}

// ===================== fallback (round-3 validated path) =====================

__global__ __launch_bounds__(256, 1)
void k_main_slow(const float* __restrict__ z, const float* __restrict__ e,
                 const float* __restrict__ Crow, const float* __restrict__ eb2,
                 float* __restrict__ out, double* __restrict__ partial) {
    __shared__ float  zt[64][LSTRIDE];
    __shared__ float  et[64][LSTRIDE];
    __shared__ float  redd[64][17];
    __shared__ int    redi[64][17];
    __shared__ int    bsel[64];
    __shared__ double lred[4];

    const int t  = threadIdx.x;
    const int tx = t & 15;
    const int ty = t >> 4;
    const int row0 = blockIdx.x * 64;

    {
        const float4* zsrc = (const float4*)(z + (size_t)row0 * DIM);
        for (int i = t; i < 64 * (DIM / 4); i += 256) {
            int r = i >> 6, c4 = i & 63;
            *(float4*)&zt[r][c4 * 4] = zsrc[r * (DIM / 4) + c4];
        }
    }
    float Cr[4];
    #pragma unroll
    for (int ri = 0; ri < 4; ++ri) Cr[ri] = Crow[row0 + ty * 4 + ri];
    float bestd[4]; int besti[4];
    #pragma unroll
    for (int ri = 0; ri < 4; ++ri) { bestd[ri] = __int_as_float(0x7f800000); besti[ri] = 0; }

    for (int kt = 0; kt < KCODES / 64; ++kt) {
        __syncthreads();
        {
            const float4* esrc = (const float4*)(e + (size_t)kt * 64 * DIM);
            for (int i = t; i < 64 * (DIM / 4); i += 256) {
                int r = i >> 6, c4 = i & 63;
                *(float4*)&et[r][c4 * 4] = esrc[r * (DIM / 4) + c4];
            }
        }
        __syncthreads();
        double acc[4][4];
        #pragma unroll
        for (int a = 0; a < 4; ++a)
            #pragma unroll
            for (int b = 0; b < 4; ++b) acc[a][b] = 0.0;
        #pragma unroll 4
        for (int d4 = 0; d4 < DIM / 4; ++d4) {
            float4 za[4], ea[4];
            #pragma unroll
            for (int ri = 0; ri < 4; ++ri) za[ri] = *(const float4*)&zt[ty * 4 + ri][d4 * 4];
            #pragma unroll
            for (int ci = 0; ci < 4; ++ci) ea[ci] = *(const float4*)&et[tx + 16 * ci][d4 * 4];
            #pragma unroll
            for (int ri = 0; ri < 4; ++ri)
                #pragma unroll
                for (int ci = 0; ci < 4; ++ci)
                    acc[ri][ci] += (double)za[ri].x * (double)ea[ci].x
                                 + (double)za[ri].y * (double)ea[ci].y
                                 + (double)za[ri].z * (double)ea[ci].z
                                 + (double)za[ri].w * (double)ea[ci].w;
        }
        #pragma unroll
        for (int ci = 0; ci < 4; ++ci) {
            int c = kt * 64 + tx + 16 * ci;
            float ebc = eb2[c];
            #pragma unroll
            for (int ri = 0; ri < 4; ++ri) {
                float d = f32_dist(Cr[ri], ebc, acc[ri][ci]);
                if (d < bestd[ri]) { bestd[ri] = d; besti[ri] = c; }
            }
        }
    }
    __syncthreads();
    #pragma unroll
    for (int ri = 0; ri < 4; ++ri) {
        redd[ty * 4 + ri][tx] = bestd[ri];
        redi[ty * 4 + ri][tx] = besti[ri];
    }
    __syncthreads();
    if (t < 64) {
        float bd = redd[t][0]; int bi = redi[t][0];
        for (int j = 1; j < 16; ++j) {
            float d = redd[t][j]; int i2 = redi[t][j];
            if (d < bd || (d == bd && i2 < bi)) { bd = d; bi = i2; }
        }
        bsel[t] = bi;
        out[1 + (size_t)NROWS * DIM + row0 + t] = (float)bi;
    }
    __syncthreads();
    double lacc = 0.0;
    {
        int r = t >> 2, qd = (t & 3) * 64;
        int bi = bsel[r];
        const float* qrow = e + (size_t)bi * DIM + qd;
        float* orow = out + 1 + (size_t)(row0 + r) * DIM + qd;
        #pragma unroll 4
        for (int d = 0; d < 64; ++d) {
            float qv = qrow[d], zv = zt[r][qd + d];
            double df = (double)qv - (double)zv;
            lacc += df * df;
            orow[d] = qv;
        }
    }
    for (int off = 32; off > 0; off >>= 1) lacc += __shfl_down(lacc, off, 64);
    if ((t & 63) == 0) lred[t >> 6] = lacc;
    __syncthreads();
    if (t == 0) partial[blockIdx.x] = lred[0] + lred[1] + lred[2] + lred[3];
}

// ============================ launch ============================

extern "C" void kernel_launch(void* const* d_in, const int* in_sizes, int n_in,
                              void* d_out, int out_size, void* d_ws, size_t ws_size,
                              hipStream_t stream) {
    const float* z = (const float*)d_in[0];
    const float* e = (const float*)d_in[1];
    float* out = (float*)d_out;
    char* w = (char*)d_ws;

    size_t o = 0;
    auto take = [&](size_t b) { size_t r = o; o = (o + b + 255) & ~(size_t)255; return r; };
    size_t o_zh = take((size_t)NROWS * DIM * 2);
    size_t o_eh = take((size_t)KCODES * DIM * 2);
    size_t o_cr = take((size_t)NROWS * 4);
    size_t o_eb = take((size_t)KCODES * 4);
    size_t o_tk = take((size_t)32 * NROWS * 8);
    size_t o_fk = take((size_t)NROWS * 8);
    size_t o_cn = take(128);
    size_t o_ls = take((size_t)32 * NROWS * 4);
    size_t o_pt = take((size_t)2048 * 8);
    size_t need = o;

    if (ws_size >= need) {
        ushort* zh = (ushort*)(w + o_zh);
        ushort* eh = (ushort*)(w + o_eh);
        float* Cr  = (float*)(w + o_cr);
        float* eb  = (float*)(w + o_eb);
        u64*   tk  = (u64*)(w + o_tk);
        u64*   fk  = (u64*)(w + o_fk);
        int*   cn  = (int*)(w + o_cn);
        int*   ls  = (int*)(w + o_ls);
        double* pt = (double*)(w + o_pt);

        k_split<<<NROWS * DIM / 8 / 256, 256, 0, stream>>>(z, zh, NROWS * DIM / 8);
        k_split<<<KCODES * DIM / 8 / 256, 256, 0, stream>>>(e, eh, KCODES * DIM / 8);
        k_rownorm<<<NROWS / 256, 256, 0, stream>>>(z, Cr, NROWS);
        k_rownorm<<<KCODES / 256, 256, 0, stream>>>(e, eb, KCODES);
        k_init<<<NROWS / 256, 256, 0, stream>>>(fk, cn);
        k_gemm<<<512 * 32, 256, 0, stream>>>(zh, eh, Cr, eb, tk);
        k_lists<<<NROWS / 256, 256, 0, stream>>>(tk, cn, ls);
        dim3 ge(32, 256);
        k_exact<<<ge, 256, 0, stream>>>(z, e, Cr, eb, ls, cn, fk);
        k_gather<<<NROWS / 32, 256, 0, stream>>>(z, e, fk, out, pt);
        k_finish<<<1, 256, 0, stream>>>(pt, out, 2048);
    } else {
        float* Cr  = (float*)w;
        float* eb  = Cr + NROWS;
        double* pt = (double*)(eb + KCODES);
        k_rownorm<<<NROWS / 256, 256, 0, stream>>>(z, Cr, NROWS);
        k_rownorm<<<KCODES / 256, 256, 0, stream>>>(e, eb, KCODES);
        k_main_slow<<<NROWS / 64, 256, 0, stream>>>(z, e, Cr, eb, out, pt);
        k_finish<<<1, 256, 0, stream>>>(pt, out, NROWS / 64);
    }
}

// Round 5
// 1044.394 us; speedup vs baseline: 5.8278x; 1.1663x over previous
//
#include <hip/hip_runtime.h>

#define KCODES 4096
#define DIM    256
#define NROWS  65536
#define MARGIN 4.0e-4f
#define LSTRIDE (DIM + 4)

typedef unsigned long long u64;
typedef unsigned int  uint;
typedef unsigned short ushort;
typedef __attribute__((ext_vector_type(8))) short bf16x8;
typedef __attribute__((ext_vector_type(4))) float f32x4;

typedef __attribute__((address_space(3))) uint lds_u32_t;
typedef __attribute__((address_space(1))) uint glb_u32_t;

__device__ __forceinline__ void g2lds16(const void* g, void* l) {
    // async global->LDS, 16B/lane; LDS dest = wave-uniform base + lane*16
    __builtin_amdgcn_global_load_lds((const glb_u32_t*)g, (lds_u32_t*)l, 16, 0, 0);
}

// ============================ shared helpers ============================

__device__ __forceinline__ float np_half_sum128(const float4* __restrict__ p4) {
    #pragma clang fp contract(off)
    float4 v0 = p4[0], v1 = p4[1];
    float r0 = v0.x * v0.x, r1 = v0.y * v0.y, r2 = v0.z * v0.z, r3 = v0.w * v0.w;
    float r4 = v1.x * v1.x, r5 = v1.y * v1.y, r6 = v1.z * v1.z, r7 = v1.w * v1.w;
    #pragma unroll
    for (int i = 1; i < 16; ++i) {
        float4 a = p4[2 * i], b = p4[2 * i + 1];
        r0 += a.x * a.x; r1 += a.y * a.y; r2 += a.z * a.z; r3 += a.w * a.w;
        r4 += b.x * b.x; r5 += b.y * b.y; r6 += b.z * b.z; r7 += b.w * b.w;
    }
    return ((r0 + r1) + (r2 + r3)) + ((r4 + r5) + (r6 + r7));
}

__global__ void k_rownorm(const float* __restrict__ src, float* __restrict__ dst, int nrows) {
    int r = blockIdx.x * blockDim.x + threadIdx.x;
    if (r >= nrows) return;
    const float4* p4 = (const float4*)(src + (size_t)r * DIM);
    float s;
    {
        #pragma clang fp contract(off)
        s = np_half_sum128(p4) + np_half_sum128(p4 + 32);
    }
    dst[r] = s;
}

// validated (round 3): fl32( fl32(Cr+ebc) - fl32(2*fl32(cross_exact)) )
__device__ __forceinline__ float f32_dist(float Cr, float ebc, double accv) {
    #pragma clang fp contract(off)
    float A = Cr + ebc;
    float B = 2.0f * (float)accv;
    return A - B;
}

__device__ __forceinline__ ushort f2bf(float f) {
    uint u = __float_as_uint(f);
    return (ushort)((u + 0x7fffu + ((u >> 16) & 1u)) >> 16);
}

// ============================ fast-path kernels ============================

__global__ void k_split(const float* __restrict__ src, ushort* __restrict__ dst, int n8) {
    int i = blockIdx.x * blockDim.x + threadIdx.x;
    if (i >= n8) return;
    const float4* s4 = (const float4*)src;
    float4 a = s4[2 * i], b = s4[2 * i + 1];
    uint4 ov;
    ov.x = (uint)f2bf(a.x) | ((uint)f2bf(a.y) << 16);
    ov.y = (uint)f2bf(a.z) | ((uint)f2bf(a.w) << 16);
    ov.z = (uint)f2bf(b.x) | ((uint)f2bf(b.y) << 16);
    ov.w = (uint)f2bf(b.z) | ((uint)f2bf(b.w) << 16);
    *(uint4*)&dst[8 * i] = ov;
}

__global__ void k_init(int* __restrict__ cnt) {
    cnt[threadIdx.x] = 0;
}

// MFMA filter GEMM, m97 structure: global_load_lds w16, linear LDS, BK=64 dbuf.
// Output: per-(128-code tile, row) min fast distance (f32 only).
__global__ __launch_bounds__(256, 2)
void k_gemm(const ushort* __restrict__ zh, const ushort* __restrict__ eh,
            const float* __restrict__ Crow, const float* __restrict__ eb2,
            float* __restrict__ tkeys) {
    __shared__ __align__(16) ushort As[2][128 * 64];   // [row][k] linear
    __shared__ __align__(16) ushort Bs[2][128 * 64];

    const int t = threadIdx.x;
    const int lane = t & 63;
    const int wv = t >> 6;
    const int wm = wv >> 1, wn = wv & 1;
    const int l15 = lane & 15, l4 = lane >> 4;
    const int bid = blockIdx.x;
    const int ct = bid & 31, rt = bid >> 5;
    const int row0 = rt * 128, col0 = ct * 128;

    f32x4 acc[4][4];
    #pragma unroll
    for (int i = 0; i < 4; ++i)
        #pragma unroll
        for (int j = 0; j < 4; ++j) acc[i][j] = (f32x4){0.f, 0.f, 0.f, 0.f};

    const char* zb = (const char*)zh;
    const char* ebp = (const char*)eh;

    auto stage = [&](int buf, int kt) {
        #pragma unroll
        for (int i = 0; i < 4; ++i) {
            int u = t + 256 * i;
            int r = u >> 3, c = u & 7;
            g2lds16(zb + ((size_t)(row0 + r) * 512 + kt * 128 + c * 16),
                    (char*)As[buf] + u * 16);
            g2lds16(ebp + ((size_t)(col0 + r) * 512 + kt * 128 + c * 16),
                    (char*)Bs[buf] + u * 16);
        }
    };

    stage(0, 0);
    __syncthreads();   // barrier drains vmcnt(0): tile 0 resident

    for (int kt = 0; kt < 4; ++kt) {
        int buf = kt & 1;
        if (kt < 3) stage(buf ^ 1, kt + 1);   // async into other buffer
        bf16x8 af[2][4], bfv[2][4];
        #pragma unroll
        for (int ks = 0; ks < 2; ++ks) {
            #pragma unroll
            for (int mi = 0; mi < 4; ++mi) {
                int rA = wm * 64 + mi * 16 + l15;
                af[ks][mi] = *(const bf16x8*)&As[buf][rA * 64 + ks * 32 + l4 * 8];
            }
            #pragma unroll
            for (int ni = 0; ni < 4; ++ni) {
                int rB = wn * 64 + ni * 16 + l15;
                bfv[ks][ni] = *(const bf16x8*)&Bs[buf][rB * 64 + ks * 32 + l4 * 8];
            }
        }
        #pragma unroll
        for (int ks = 0; ks < 2; ++ks)
            #pragma unroll
            for (int mi = 0; mi < 4; ++mi)
                #pragma unroll
                for (int ni = 0; ni < 4; ++ni)
                    acc[mi][ni] = __builtin_amdgcn_mfma_f32_16x16x32_bf16(
                        af[ks][mi], bfv[ks][ni], acc[mi][ni], 0, 0, 0);
        __syncthreads();   // drains vmcnt (next tile ready) + lgkmcnt
    }

    // ---- epilogue: per-row min fast distance over this block's 128 codes ----
    // D-frag (m89): col = lane&15, row = (lane>>4)*4 + reg.
    float* table = (float*)&As[0][0];   // [128][33] f32 (+1 pad: conflict-free)
    float eb[4];
    #pragma unroll
    for (int ni = 0; ni < 4; ++ni) eb[ni] = eb2[col0 + wn * 64 + ni * 16 + l15];

    #pragma unroll
    for (int mi = 0; mi < 4; ++mi) {
        #pragma unroll
        for (int rg = 0; rg < 4; ++rg) {
            int rloc = wm * 64 + mi * 16 + l4 * 4 + rg;
            float Cr = Crow[row0 + rloc];
            float dmin = __int_as_float(0x7f800000);
            #pragma unroll
            for (int ni = 0; ni < 4; ++ni) {
                float d;
                {
                    #pragma clang fp contract(off)
                    float A = Cr + eb[ni];
                    d = A - 2.0f * acc[mi][ni][rg];
                }
                dmin = fminf(dmin, d);
            }
            table[rloc * 33 + wn * 16 + l15] = dmin;
        }
    }
    __syncthreads();
    if (t < 128) {
        float m = table[t * 33];
        #pragma unroll 8
        for (int j = 1; j < 32; ++j) m = fminf(m, table[t * 33 + j]);
        tkeys[(size_t)ct * NROWS + row0 + t] = m;
    }
}

// per row: best over 32 tiles -> cutoff; wave-aggregated list append; fkey init
__global__ void k_lists(const float* __restrict__ tkeys, int* __restrict__ cnt,
                        int* __restrict__ list, u64* __restrict__ fkey) {
    int row = blockIdx.x * 256 + threadIdx.x;
    int lane = threadIdx.x & 63;
    float tv[32];
    float best = __int_as_float(0x7f800000);
    #pragma unroll
    for (int tt = 0; tt < 32; ++tt) {
        tv[tt] = tkeys[(size_t)tt * NROWS + row];
        best = fminf(best, tv[tt]);
    }
    fkey[row] = ~0ull;   // init for k_exact's atomicMin
    float cutoff = best + MARGIN;
    #pragma unroll 4
    for (int tt = 0; tt < 32; ++tt) {
        bool pred = tv[tt] <= cutoff;
        u64 mask = __ballot(pred);
        if (mask) {
            int nq = __popcll(mask);
            int rank = __popcll(mask & ((1ull << lane) - 1ull));
            int base = 0;
            if (lane == 0) base = atomicAdd(&cnt[tt], nq);
            base = __shfl(base, 0, 64);
            if (pred) list[tt * NROWS + base + rank] = row;
        }
    }
}

// exact decider: validated f64-cross (4 independent accumulators; order-free
// since f64 err ~1e-15 << f32 half-ulp ~2e-9) + f32_dist + lexicographic key.
__global__ __launch_bounds__(256)
void k_exact(const float* __restrict__ z, const float* __restrict__ e,
             const float* __restrict__ Crow, const float* __restrict__ eb2,
             const int* __restrict__ list, const int* __restrict__ cnt,
             u64* __restrict__ fkey) {
    __shared__ __align__(16) float zx[16][260];
    __shared__ __align__(16) float ex[32][260];
    __shared__ int rows[16];
    const int tile = blockIdx.x;
    const int nct = cnt[tile];
    const int t = threadIdx.x;
    const int rl = t & 15;
    const int cs = t >> 4;

    for (int chunk = blockIdx.y; chunk * 16 < nct; chunk += gridDim.y) {
        int base = chunk * 16;
        int nr = nct - base; if (nr > 16) nr = 16;
        __syncthreads();
        if (t < 16) rows[t] = list[tile * NROWS + base + (t < nr ? t : 0)];
        __syncthreads();
        {
            int rr = t >> 4, c = t & 15;
            const float4* src = (const float4*)(z + (size_t)rows[rr] * DIM);
            float4* dstrow = (float4*)zx[rr];
            #pragma unroll
            for (int j = 0; j < 4; ++j) dstrow[c + 16 * j] = src[c + 16 * j];
        }
        u64 kbest = ~0ull;
        int myrow = rows[rl];
        float Cr = Crow[myrow];
        for (int s = 0; s < 4; ++s) {
            __syncthreads();
            {
                int cc = t >> 3, c8 = t & 7;
                int code = tile * 128 + s * 32 + cc;
                const float4* src = (const float4*)(e + (size_t)code * DIM);
                float4* dstrow = (float4*)ex[cc];
                #pragma unroll
                for (int j = 0; j < 8; ++j) dstrow[c8 + 8 * j] = src[c8 + 8 * j];
            }
            __syncthreads();
            #pragma unroll
            for (int cj = 0; cj < 2; ++cj) {
                int cl = cs + 16 * cj;
                int cglob = tile * 128 + s * 32 + cl;
                double a0 = 0.0, a1 = 0.0, a2 = 0.0, a3 = 0.0;
                const float4* za  = (const float4*)zx[rl];
                const float4* eb_ = (const float4*)ex[cl];
                #pragma unroll 8
                for (int d4 = 0; d4 < 64; ++d4) {
                    float4 x = za[d4], y = eb_[d4];
                    a0 += (double)x.x * (double)y.x;
                    a1 += (double)x.y * (double)y.y;
                    a2 += (double)x.z * (double)y.z;
                    a3 += (double)x.w * (double)y.w;
                }
                float d = f32_dist(Cr, eb2[cglob], (a0 + a1) + (a2 + a3));
                u64 key = ((u64)__float_as_uint(d) << 32) | (u64)cglob;
                kbest = key < kbest ? key : kbest;
            }
        }
        atomicMin((unsigned long long*)&fkey[myrow], kbest);
    }
}

__global__ __launch_bounds__(256)
void k_gather(const float* __restrict__ z, const float* __restrict__ e,
              const u64* __restrict__ fkey, float* __restrict__ out,
              double* __restrict__ partial) {
    __shared__ double lred[4];
    const int t = threadIdx.x;
    const int row = blockIdx.x * 32 + (t >> 3);
    const int c8 = t & 7;
    const int idx = (int)(fkey[row] & 0xffffffffull);
    if (c8 == 0) out[1 + (size_t)NROWS * DIM + row] = (float)idx;
    const float4* zr = (const float4*)(z + (size_t)row * DIM);
    const float4* er = (const float4*)(e + (size_t)idx * DIM);
    float4* orow = (float4*)(out + 1 + (size_t)row * DIM);
    double lacc = 0.0;
    #pragma unroll
    for (int j = 0; j < 8; ++j) {
        float4 q = er[c8 + 8 * j];
        float4 zv = zr[c8 + 8 * j];
        orow[c8 + 8 * j] = q;
        double d0 = (double)q.x - (double)zv.x;
        double d1 = (double)q.y - (double)zv.y;
        double d2 = (double)q.z - (double)zv.z;
        double d3 = (double)q.w - (double)zv.w;
        lacc += d0 * d0 + d1 * d1 + d2 * d2 + d3 * d3;
    }
    for (int off = 32; off > 0; off >>= 1) lacc += __shfl_down(lacc, off, 64);
    if ((t & 63) == 0) lred[t >> 6] = lacc;
    __syncthreads();
    if (t == 0) partial[blockIdx.x] = lred[0] + lred[1] + lred[2] + lred[3];
}

__global__ void k_finish(const double* __restrict__ partial, float* __restrict__ out, int n) {
    __shared__ double s[256];
    double a = 0.0;
    for (int i = threadIdx.x; i < n; i += 256) a += partial[i];
    s[threadIdx.x] = a;
    __syncthreads();
    for (int off = 128; off > 0; off >>= 1) {
        if (threadIdx.x < off) s[threadIdx.x] += s[threadIdx.x + off];
        __syncthreads();
    }
    if (threadIdx.x == 0)
        out[0] = (float)(1.25 * s[0] / ((double)NROWS * (double)DIM));
}

// ===================== fallback (round-3 validated path) =====================

__global__ __launch_bounds__(256, 1)
void k_main_slow(const float* __restrict__ z, const float* __restrict__ e,
                 const float* __restrict__ Crow, const float* __restrict__ eb2,
                 float* __restrict__ out, double* __restrict__ partial) {
    __shared__ float  zt[64][LSTRIDE];
    __shared__ float  et[64][LSTRIDE];
    __shared__ float  redd[64][17];
    __shared__ int    redi[64][17];
    __shared__ int    bsel[64];
    __shared__ double lred[4];

    const int t  = threadIdx.x;
    const int tx = t & 15;
    const int ty = t >> 4;
    const int row0 = blockIdx.x * 64;

    {
        const float4* zsrc = (const float4*)(z + (size_t)row0 * DIM);
        for (int i = t; i < 64 * (DIM / 4); i += 256) {
            int r = i >> 6, c4 = i & 63;
            *(float4*)&zt[r][c4 * 4] = zsrc[r * (DIM / 4) + c4];
        }
    }
    float Cr[4];
    #pragma unroll
    for (int ri = 0; ri < 4; ++ri) Cr[ri] = Crow[row0 + ty * 4 + ri];
    float bestd[4]; int besti[4];
    #pragma unroll
    for (int ri = 0; ri < 4; ++ri) { bestd[ri] = __int_as_float(0x7f800000); besti[ri] = 0; }

    for (int kt = 0; kt < KCODES / 64; ++kt) {
        __syncthreads();
        {
            const float4* esrc = (const float4*)(e + (size_t)kt * 64 * DIM);
            for (int i = t; i < 64 * (DIM / 4); i += 256) {
                int r = i >> 6, c4 = i & 63;
                *(float4*)&et[r][c4 * 4] = esrc[r * (DIM / 4) + c4];
            }
        }
        __syncthreads();
        double acc[4][4];
        #pragma unroll
        for (int a = 0; a < 4; ++a)
            #pragma unroll
            for (int b = 0; b < 4; ++b) acc[a][b] = 0.0;
        #pragma unroll 4
        for (int d4 = 0; d4 < DIM / 4; ++d4) {
            float4 za[4], ea[4];
            #pragma unroll
            for (int ri = 0; ri < 4; ++ri) za[ri] = *(const float4*)&zt[ty * 4 + ri][d4 * 4];
            #pragma unroll
            for (int ci = 0; ci < 4; ++ci) ea[ci] = *(const float4*)&et[tx + 16 * ci][d4 * 4];
            #pragma unroll
            for (int ri = 0; ri < 4; ++ri)
                #pragma unroll
                for (int ci = 0; ci < 4; ++ci)
                    acc[ri][ci] += (double)za[ri].x * (double)ea[ci].x
                                 + (double)za[ri].y * (double)ea[ci].y
                                 + (double)za[ri].z * (double)ea[ci].z
                                 + (double)za[ri].w * (double)ea[ci].w;
        }
        #pragma unroll
        for (int ci = 0; ci < 4; ++ci) {
            int c = kt * 64 + tx + 16 * ci;
            float ebc = eb2[c];
            #pragma unroll
            for (int ri = 0; ri < 4; ++ri) {
                float d = f32_dist(Cr[ri], ebc, acc[ri][ci]);
                if (d < bestd[ri]) { bestd[ri] = d; besti[ri] = c; }
            }
        }
    }
    __syncthreads();
    #pragma unroll
    for (int ri = 0; ri < 4; ++ri) {
        redd[ty * 4 + ri][tx] = bestd[ri];
        redi[ty * 4 + ri][tx] = besti[ri];
    }
    __syncthreads();
    if (t < 64) {
        float bd = redd[t][0]; int bi = redi[t][0];
        for (int j = 1; j < 16; ++j) {
            float d = redd[t][j]; int i2 = redi[t][j];
            if (d < bd || (d == bd && i2 < bi)) { bd = d; bi = i2; }
        }
        bsel[t] = bi;
        out[1 + (size_t)NROWS * DIM + row0 + t] = (float)bi;
    }
    __syncthreads();
    double lacc = 0.0;
    {
        int r = t >> 2, qd = (t & 3) * 64;
        int bi = bsel[r];
        const float* qrow = e + (size_t)bi * DIM + qd;
        float* orow = out + 1 + (size_t)(row0 + r) * DIM + qd;
        #pragma unroll 4
        for (int d = 0; d < 64; ++d) {
            float qv = qrow[d], zv = zt[r][qd + d];
            double df = (double)qv - (double)zv;
            lacc += df * df;
            orow[d] = qv;
        }
    }
    for (int off = 32; off > 0; off >>= 1) lacc += __shfl_down(lacc, off, 64);
    if ((t & 63) == 0) lred[t >> 6] = lacc;
    __syncthreads();
    if (t == 0) partial[blockIdx.x] = lred[0] + lred[1] + lred[2] + lred[3];
}

// ============================ launch ============================

extern "C" void kernel_launch(void* const* d_in, const int* in_sizes, int n_in,
                              void* d_out, int out_size, void* d_ws, size_t ws_size,
                              hipStream_t stream) {
    const float* z = (const float*)d_in[0];
    const float* e = (const float*)d_in[1];
    float* out = (float*)d_out;
    char* w = (char*)d_ws;

    size_t o = 0;
    auto take = [&](size_t b) { size_t r = o; o = (o + b + 255) & ~(size_t)255; return r; };
    size_t o_zh = take((size_t)NROWS * DIM * 2);
    size_t o_eh = take((size_t)KCODES * DIM * 2);
    size_t o_cr = take((size_t)NROWS * 4);
    size_t o_eb = take((size_t)KCODES * 4);
    size_t o_tk = take((size_t)32 * NROWS * 4);
    size_t o_fk = take((size_t)NROWS * 8);
    size_t o_cn = take(128);
    size_t o_ls = take((size_t)32 * NROWS * 4);
    size_t o_pt = take((size_t)2048 * 8);
    size_t need = o;

    if (ws_size >= need) {
        ushort* zh = (ushort*)(w + o_zh);
        ushort* eh = (ushort*)(w + o_eh);
        float* Cr  = (float*)(w + o_cr);
        float* eb  = (float*)(w + o_eb);
        float* tk  = (float*)(w + o_tk);
        u64*   fk  = (u64*)(w + o_fk);
        int*   cn  = (int*)(w + o_cn);
        int*   ls  = (int*)(w + o_ls);
        double* pt = (double*)(w + o_pt);

        k_split<<<NROWS * DIM / 8 / 256, 256, 0, stream>>>(z, zh, NROWS * DIM / 8);
        k_split<<<KCODES * DIM / 8 / 256, 256, 0, stream>>>(e, eh, KCODES * DIM / 8);
        k_rownorm<<<NROWS / 256, 256, 0, stream>>>(z, Cr, NROWS);
        k_rownorm<<<KCODES / 256, 256, 0, stream>>>(e, eb, KCODES);
        k_init<<<1, 32, 0, stream>>>(cn);
        k_gemm<<<512 * 32, 256, 0, stream>>>(zh, eh, Cr, eb, tk);
        k_lists<<<NROWS / 256, 256, 0, stream>>>(tk, cn, ls, fk);
        dim3 ge(32, 256);
        k_exact<<<ge, 256, 0, stream>>>(z, e, Cr, eb, ls, cn, fk);
        k_gather<<<NROWS / 32, 256, 0, stream>>>(z, e, fk, out, pt);
        k_finish<<<1, 256, 0, stream>>>(pt, out, 2048);
    } else {
        float* Cr  = (float*)w;
        float* eb  = Cr + NROWS;
        double* pt = (double*)(eb + KCODES);
        k_rownorm<<<NROWS / 256, 256, 0, stream>>>(z, Cr, NROWS);
        k_rownorm<<<KCODES / 256, 256, 0, stream>>>(e, eb, KCODES);
        k_main_slow<<<NROWS / 64, 256, 0, stream>>>(z, e, Cr, eb, out, pt);
        k_finish<<<1, 256, 0, stream>>>(pt, out, NROWS / 64);
    }
}

// Round 6
// 818.245 us; speedup vs baseline: 7.4385x; 1.2764x over previous
//
#include <hip/hip_runtime.h>

#define KCODES 4096
#define DIM    256
#define NROWS  65536
#define MARGIN 4.0e-4f
#define DSLACK 3.0e-5f      // decode slack for u8-quantized subtile deltas
#define LCAP   4096         // per-subtile candidate list capacity (avg ~665)
#define LSTRIDE (DIM + 4)

typedef unsigned long long u64;
typedef unsigned int  uint;
typedef unsigned short ushort;
typedef __attribute__((ext_vector_type(8))) short bf16x8;
typedef __attribute__((ext_vector_type(4))) float f32x4;

typedef __attribute__((address_space(3))) uint lds_u32_t;
typedef __attribute__((address_space(1))) uint glb_u32_t;

__device__ __forceinline__ void g2lds16(const void* g, void* l) {
    __builtin_amdgcn_global_load_lds((const glb_u32_t*)g, (lds_u32_t*)l, 16, 0, 0);
}

// ============================ shared helpers ============================

__device__ __forceinline__ float np_half_sum128(const float4* __restrict__ p4) {
    #pragma clang fp contract(off)
    float4 v0 = p4[0], v1 = p4[1];
    float r0 = v0.x * v0.x, r1 = v0.y * v0.y, r2 = v0.z * v0.z, r3 = v0.w * v0.w;
    float r4 = v1.x * v1.x, r5 = v1.y * v1.y, r6 = v1.z * v1.z, r7 = v1.w * v1.w;
    #pragma unroll
    for (int i = 1; i < 16; ++i) {
        float4 a = p4[2 * i], b = p4[2 * i + 1];
        r0 += a.x * a.x; r1 += a.y * a.y; r2 += a.z * a.z; r3 += a.w * a.w;
        r4 += b.x * b.x; r5 += b.y * b.y; r6 += b.z * b.z; r7 += b.w * b.w;
    }
    return ((r0 + r1) + (r2 + r3)) + ((r4 + r5) + (r6 + r7));
}

__global__ void k_rownorm(const float* __restrict__ src, float* __restrict__ dst, int nrows) {
    int r = blockIdx.x * blockDim.x + threadIdx.x;
    if (r >= nrows) return;
    const float4* p4 = (const float4*)(src + (size_t)r * DIM);
    float s;
    {
        #pragma clang fp contract(off)
        s = np_half_sum128(p4) + np_half_sum128(p4 + 32);
    }
    dst[r] = s;
}

// validated (round 3): fl32( fl32(Cr+ebc) - fl32(2*fl32(cross_exact)) )
__device__ __forceinline__ float f32_dist(float Cr, float ebc, double accv) {
    #pragma clang fp contract(off)
    float A = Cr + ebc;
    float B = 2.0f * (float)accv;
    return A - B;
}

__device__ __forceinline__ ushort f2bf(float f) {
    uint u = __float_as_uint(f);
    return (ushort)((u + 0x7fffu + ((u >> 16) & 1u)) >> 16);
}

// ============================ fast-path kernels ============================

__global__ void k_split(const float* __restrict__ src, ushort* __restrict__ dst, int n8) {
    int i = blockIdx.x * blockDim.x + threadIdx.x;
    if (i >= n8) return;
    const float4* s4 = (const float4*)src;
    float4 a = s4[2 * i], b = s4[2 * i + 1];
    uint4 ov;
    ov.x = (uint)f2bf(a.x) | ((uint)f2bf(a.y) << 16);
    ov.y = (uint)f2bf(a.z) | ((uint)f2bf(a.w) << 16);
    ov.z = (uint)f2bf(b.x) | ((uint)f2bf(b.y) << 16);
    ov.w = (uint)f2bf(b.z) | ((uint)f2bf(b.w) << 16);
    *(uint4*)&dst[8 * i] = ov;
}

__global__ void k_init(int* __restrict__ cnt) {
    cnt[threadIdx.x] = 0;
}

// MFMA filter GEMM (m97 structure). Output per (row, 128-tile): tile-min f32
// + 4 per-32-code-subtile deltas (u8, quantum 1e-5, floor => conservative).
__global__ __launch_bounds__(256, 2)
void k_gemm(const ushort* __restrict__ zh, const ushort* __restrict__ eh,
            const float* __restrict__ Crow, const float* __restrict__ eb2,
            float* __restrict__ tk, uint* __restrict__ tk2) {
    __shared__ __align__(16) ushort smem[2][2][128 * 64];  // [buf][A=0/B=1][row*64+k]

    const int t = threadIdx.x;
    const int lane = t & 63;
    const int wv = t >> 6;
    const int wm = wv >> 1, wn = wv & 1;
    const int l15 = lane & 15, l4 = lane >> 4;
    const int bid = blockIdx.x;
    const int ct = bid & 31, rt = bid >> 5;
    const int row0 = rt * 128, col0 = ct * 128;

    f32x4 acc[4][4];
    #pragma unroll
    for (int i = 0; i < 4; ++i)
        #pragma unroll
        for (int j = 0; j < 4; ++j) acc[i][j] = (f32x4){0.f, 0.f, 0.f, 0.f};

    const char* zb = (const char*)zh;
    const char* ebp = (const char*)eh;

    auto stage = [&](int buf, int kt) {
        #pragma unroll
        for (int i = 0; i < 4; ++i) {
            int u = t + 256 * i;
            int r = u >> 3, c = u & 7;
            g2lds16(zb + ((size_t)(row0 + r) * 512 + kt * 128 + c * 16),
                    (char*)smem[buf][0] + u * 16);
            g2lds16(ebp + ((size_t)(col0 + r) * 512 + kt * 128 + c * 16),
                    (char*)smem[buf][1] + u * 16);
        }
    };

    stage(0, 0);
    __syncthreads();

    for (int kt = 0; kt < 4; ++kt) {
        int buf = kt & 1;
        if (kt < 3) stage(buf ^ 1, kt + 1);
        bf16x8 af[2][4], bfv[2][4];
        #pragma unroll
        for (int ks = 0; ks < 2; ++ks) {
            #pragma unroll
            for (int mi = 0; mi < 4; ++mi) {
                int rA = wm * 64 + mi * 16 + l15;
                af[ks][mi] = *(const bf16x8*)&smem[buf][0][rA * 64 + ks * 32 + l4 * 8];
            }
            #pragma unroll
            for (int ni = 0; ni < 4; ++ni) {
                int rB = wn * 64 + ni * 16 + l15;
                bfv[ks][ni] = *(const bf16x8*)&smem[buf][1][rB * 64 + ks * 32 + l4 * 8];
            }
        }
        #pragma unroll
        for (int ks = 0; ks < 2; ++ks)
            #pragma unroll
            for (int mi = 0; mi < 4; ++mi)
                #pragma unroll
                for (int ni = 0; ni < 4; ++ni)
                    acc[mi][ni] = __builtin_amdgcn_mfma_f32_16x16x32_bf16(
                        af[ks][mi], bfv[ks][ni], acc[mi][ni], 0, 0, 0);
        __syncthreads();
    }

    // ---- epilogue: per-(row, 32-code subtile) mins ----
    // D-frag (m89): col = lane&15, row = (lane>>4)*4 + reg.
    // table[row][ (wn*2+p)*16 + l15 ] = min over ni in {2p,2p+1}; stride 65.
    float* table = (float*)smem;   // 128*65*4 = 33.3 KB, safe after final barrier
    float eb[4];
    #pragma unroll
    for (int ni = 0; ni < 4; ++ni) eb[ni] = eb2[col0 + wn * 64 + ni * 16 + l15];

    #pragma unroll
    for (int mi = 0; mi < 4; ++mi) {
        #pragma unroll
        for (int rg = 0; rg < 4; ++rg) {
            int rloc = wm * 64 + mi * 16 + l4 * 4 + rg;
            float Cr = Crow[row0 + rloc];
            float d[4];
            #pragma unroll
            for (int ni = 0; ni < 4; ++ni) {
                #pragma clang fp contract(off)
                float A = Cr + eb[ni];
                d[ni] = A - 2.0f * acc[mi][ni][rg];
            }
            table[rloc * 65 + wn * 32 + l15]      = fminf(d[0], d[1]);
            table[rloc * 65 + wn * 32 + 16 + l15] = fminf(d[2], d[3]);
        }
    }
    __syncthreads();
    if (t < 128) {
        float m[4];
        #pragma unroll
        for (int p = 0; p < 4; ++p) {
            float v = table[t * 65 + p * 16];
            #pragma unroll
            for (int j = 1; j < 16; ++j) v = fminf(v, table[t * 65 + p * 16 + j]);
            m[p] = v;
        }
        float mt = fminf(fminf(m[0], m[1]), fminf(m[2], m[3]));
        uint pk = 0;
        #pragma unroll
        for (int p = 0; p < 4; ++p) {
            int q = (int)((m[p] - mt) * 1e5f);   // floor (nonneg) => decoded <= true
            q = q > 255 ? 255 : q;
            pk |= (uint)q << (8 * p);
        }
        tk [(size_t)ct * NROWS + row0 + t] = mt;
        tk2[(size_t)ct * NROWS + row0 + t] = pk;
    }
}

// per row: rowbest over 32 tile-mins; decode 128 subtile mins; append row to
// each subtile list within cutoff (wave-aggregated); init fkey.
__global__ void k_lists(const float* __restrict__ tk, const uint* __restrict__ tk2,
                        int* __restrict__ cnt, int* __restrict__ list,
                        u64* __restrict__ fkey) {
    int row = blockIdx.x * 256 + threadIdx.x;
    int lane = threadIdx.x & 63;
    float tm[32]; uint pk[32];
    float best = __int_as_float(0x7f800000);
    #pragma unroll
    for (int tt = 0; tt < 32; ++tt) {
        tm[tt] = tk [(size_t)tt * NROWS + row];
        pk[tt] = tk2[(size_t)tt * NROWS + row];
        best = fminf(best, tm[tt]);
    }
    fkey[row] = ~0ull;
    float cutoff = best + (MARGIN + DSLACK);
    #pragma unroll 2
    for (int tt = 0; tt < 32; ++tt) {
        #pragma unroll
        for (int p = 0; p < 4; ++p) {
            float s = tm[tt] + (float)((pk[tt] >> (8 * p)) & 255u) * 1e-5f;
            bool pred = s <= cutoff;
            u64 mask = __ballot(pred);
            if (mask) {
                int sub = tt * 4 + p;
                int nq = __popcll(mask);
                int rank = __popcll(mask & ((1ull << lane) - 1ull));
                int base = 0;
                if (lane == 0) base = atomicAdd(&cnt[sub], nq);
                base = __shfl(base, 0, 64);
                int pos = base + rank;
                if (pred && pos < LCAP) list[sub * LCAP + pos] = row;
            }
        }
    }
}

// exact decider per (subtile, row-chunk): e-subtile staged once per block,
// 32-row chunks, 2x2 register blocking. Validated f64-cross + f32_dist +
// lexicographic (d,idx) key, atomicMin-merged.
__global__ __launch_bounds__(256, 2)
void k_exact(const float* __restrict__ z, const float* __restrict__ e,
             const float* __restrict__ Crow, const float* __restrict__ eb2,
             const int* __restrict__ list, const int* __restrict__ cnt,
             u64* __restrict__ fkey) {
    __shared__ __align__(16) float ex[32][260];
    __shared__ __align__(16) float zx[32][260];
    __shared__ int rows[32];
    __shared__ u64 keytab[32][17];
    const int sub = blockIdx.x;       // 0..127
    const int nct = cnt[sub];
    const int t = threadIdx.x;
    const int rp = t & 15, cq = t >> 4;

    {   // stage e subtile (32 codes x 256) once; covered by first loop barrier
        int cc = t >> 3, c8 = t & 7;
        const float4* src = (const float4*)(e + (size_t)(sub * 32 + cc) * DIM);
        float4* dr = (float4*)ex[cc];
        #pragma unroll
        for (int j = 0; j < 8; ++j) dr[c8 + 8 * j] = src[c8 + 8 * j];
    }
    const float ebc0 = eb2[sub * 32 + cq];
    const float ebc1 = eb2[sub * 32 + 16 + cq];
    const int c0 = sub * 32 + cq, c1 = sub * 32 + 16 + cq;

    for (int base = blockIdx.y * 32; base < nct; base += gridDim.y * 32) {
        __syncthreads();   // prior iter's keytab/rows reads done; e-stage done
        if (t < 32) {
            int i = base + t;
            rows[t] = list[sub * LCAP + (i < nct ? i : nct - 1)];
        }
        __syncthreads();
        {   // stage 32 z rows
            int rr = t >> 3, c8 = t & 7;
            const float4* src = (const float4*)(z + (size_t)rows[rr] * DIM);
            float4* dr = (float4*)zx[rr];
            #pragma unroll
            for (int j = 0; j < 8; ++j) dr[c8 + 8 * j] = src[c8 + 8 * j];
        }
        __syncthreads();

        double a00 = 0.0, a01 = 0.0, a10 = 0.0, a11 = 0.0;
        const float4* z0 = (const float4*)zx[rp];
        const float4* z1 = (const float4*)zx[rp + 16];
        const float4* e0 = (const float4*)ex[cq];
        const float4* e1 = (const float4*)ex[cq + 16];
        #pragma unroll 8
        for (int d4 = 0; d4 < 64; ++d4) {
            float4 x0 = z0[d4], x1 = z1[d4], y0 = e0[d4], y1 = e1[d4];
            a00 += (double)x0.x * (double)y0.x; a00 += (double)x0.y * (double)y0.y;
            a00 += (double)x0.z * (double)y0.z; a00 += (double)x0.w * (double)y0.w;
            a01 += (double)x0.x * (double)y1.x; a01 += (double)x0.y * (double)y1.y;
            a01 += (double)x0.z * (double)y1.z; a01 += (double)x0.w * (double)y1.w;
            a10 += (double)x1.x * (double)y0.x; a10 += (double)x1.y * (double)y0.y;
            a10 += (double)x1.z * (double)y0.z; a10 += (double)x1.w * (double)y0.w;
            a11 += (double)x1.x * (double)y1.x; a11 += (double)x1.y * (double)y1.y;
            a11 += (double)x1.z * (double)y1.z; a11 += (double)x1.w * (double)y1.w;
        }
        int r0 = rows[rp], r1 = rows[rp + 16];
        float C0 = Crow[r0], C1 = Crow[r1];
        u64 k00 = ((u64)__float_as_uint(f32_dist(C0, ebc0, a00)) << 32) | (u64)c0;
        u64 k01 = ((u64)__float_as_uint(f32_dist(C0, ebc1, a01)) << 32) | (u64)c1;
        u64 k10 = ((u64)__float_as_uint(f32_dist(C1, ebc0, a10)) << 32) | (u64)c0;
        u64 k11 = ((u64)__float_as_uint(f32_dist(C1, ebc1, a11)) << 32) | (u64)c1;
        keytab[rp][cq]      = k00 < k01 ? k00 : k01;
        keytab[rp + 16][cq] = k10 < k11 ? k10 : k11;
        __syncthreads();
        if (t < 32) {
            u64 kb = keytab[t][0];
            #pragma unroll
            for (int j = 1; j < 16; ++j) {
                u64 k = keytab[t][j];
                kb = k < kb ? k : kb;
            }
            atomicMin((unsigned long long*)&fkey[rows[t]], kb);
        }
    }
}

__global__ __launch_bounds__(256)
void k_gather(const float* __restrict__ z, const float* __restrict__ e,
              const u64* __restrict__ fkey, float* __restrict__ out,
              double* __restrict__ partial) {
    __shared__ double lred[4];
    const int t = threadIdx.x;
    const int row = blockIdx.x * 32 + (t >> 3);
    const int c8 = t & 7;
    const int idx = (int)(fkey[row] & 0xffffffffull);
    if (c8 == 0) out[1 + (size_t)NROWS * DIM + row] = (float)idx;
    const float4* zr = (const float4*)(z + (size_t)row * DIM);
    const float4* er = (const float4*)(e + (size_t)idx * DIM);
    float4* orow = (float4*)(out + 1 + (size_t)row * DIM);
    double lacc = 0.0;
    #pragma unroll
    for (int j = 0; j < 8; ++j) {
        float4 q = er[c8 + 8 * j];
        float4 zv = zr[c8 + 8 * j];
        orow[c8 + 8 * j] = q;
        double d0 = (double)q.x - (double)zv.x;
        double d1 = (double)q.y - (double)zv.y;
        double d2 = (double)q.z - (double)zv.z;
        double d3 = (double)q.w - (double)zv.w;
        lacc += d0 * d0 + d1 * d1 + d2 * d2 + d3 * d3;
    }
    for (int off = 32; off > 0; off >>= 1) lacc += __shfl_down(lacc, off, 64);
    if ((t & 63) == 0) lred[t >> 6] = lacc;
    __syncthreads();
    if (t == 0) partial[blockIdx.x] = lred[0] + lred[1] + lred[2] + lred[3];
}

__global__ void k_finish(const double* __restrict__ partial, float* __restrict__ out, int n) {
    __shared__ double s[256];
    double a = 0.0;
    for (int i = threadIdx.x; i < n; i += 256) a += partial[i];
    s[threadIdx.x] = a;
    __syncthreads();
    for (int off = 128; off > 0; off >>= 1) {
        if (threadIdx.x < off) s[threadIdx.x] += s[threadIdx.x + off];
        __syncthreads();
    }
    if (threadIdx.x == 0)
        out[0] = (float)(1.25 * s[0] / ((double)NROWS * (double)DIM));
}

// ===================== fallback (round-3 validated path) =====================

__global__ __launch_bounds__(256, 1)
void k_main_slow(const float* __restrict__ z, const float* __restrict__ e,
                 const float* __restrict__ Crow, const float* __restrict__ eb2,
                 float* __restrict__ out, double* __restrict__ partial) {
    __shared__ float  zt[64][LSTRIDE];
    __shared__ float  et[64][LSTRIDE];
    __shared__ float  redd[64][17];
    __shared__ int    redi[64][17];
    __shared__ int    bsel[64];
    __shared__ double lred[4];

    const int t  = threadIdx.x;
    const int tx = t & 15;
    const int ty = t >> 4;
    const int row0 = blockIdx.x * 64;

    {
        const float4* zsrc = (const float4*)(z + (size_t)row0 * DIM);
        for (int i = t; i < 64 * (DIM / 4); i += 256) {
            int r = i >> 6, c4 = i & 63;
            *(float4*)&zt[r][c4 * 4] = zsrc[r * (DIM / 4) + c4];
        }
    }
    float Cr[4];
    #pragma unroll
    for (int ri = 0; ri < 4; ++ri) Cr[ri] = Crow[row0 + ty * 4 + ri];
    float bestd[4]; int besti[4];
    #pragma unroll
    for (int ri = 0; ri < 4; ++ri) { bestd[ri] = __int_as_float(0x7f800000); besti[ri] = 0; }

    for (int kt = 0; kt < KCODES / 64; ++kt) {
        __syncthreads();
        {
            const float4* esrc = (const float4*)(e + (size_t)kt * 64 * DIM);
            for (int i = t; i < 64 * (DIM / 4); i += 256) {
                int r = i >> 6, c4 = i & 63;
                *(float4*)&et[r][c4 * 4] = esrc[r * (DIM / 4) + c4];
            }
        }
        __syncthreads();
        double acc[4][4];
        #pragma unroll
        for (int a = 0; a < 4; ++a)
            #pragma unroll
            for (int b = 0; b < 4; ++b) acc[a][b] = 0.0;
        #pragma unroll 4
        for (int d4 = 0; d4 < DIM / 4; ++d4) {
            float4 za[4], ea[4];
            #pragma unroll
            for (int ri = 0; ri < 4; ++ri) za[ri] = *(const float4*)&zt[ty * 4 + ri][d4 * 4];
            #pragma unroll
            for (int ci = 0; ci < 4; ++ci) ea[ci] = *(const float4*)&et[tx + 16 * ci][d4 * 4];
            #pragma unroll
            for (int ri = 0; ri < 4; ++ri)
                #pragma unroll
                for (int ci = 0; ci < 4; ++ci)
                    acc[ri][ci] += (double)za[ri].x * (double)ea[ci].x
                                 + (double)za[ri].y * (double)ea[ci].y
                                 + (double)za[ri].z * (double)ea[ci].z
                                 + (double)za[ri].w * (double)ea[ci].w;
        }
        #pragma unroll
        for (int ci = 0; ci < 4; ++ci) {
            int c = kt * 64 + tx + 16 * ci;
            float ebc = eb2[c];
            #pragma unroll
            for (int ri = 0; ri < 4; ++ri) {
                float d = f32_dist(Cr[ri], ebc, acc[ri][ci]);
                if (d < bestd[ri]) { bestd[ri] = d; besti[ri] = c; }
            }
        }
    }
    __syncthreads();
    #pragma unroll
    for (int ri = 0; ri < 4; ++ri) {
        redd[ty * 4 + ri][tx] = bestd[ri];
        redi[ty * 4 + ri][tx] = besti[ri];
    }
    __syncthreads();
    if (t < 64) {
        float bd = redd[t][0]; int bi = redi[t][0];
        for (int j = 1; j < 16; ++j) {
            float d = redd[t][j]; int i2 = redi[t][j];
            if (d < bd || (d == bd && i2 < bi)) { bd = d; bi = i2; }
        }
        bsel[t] = bi;
        out[1 + (size_t)NROWS * DIM + row0 + t] = (float)bi;
    }
    __syncthreads();
    double lacc = 0.0;
    {
        int r = t >> 2, qd = (t & 3) * 64;
        int bi = bsel[r];
        const float* qrow = e + (size_t)bi * DIM + qd;
        float* orow = out + 1 + (size_t)(row0 + r) * DIM + qd;
        #pragma unroll 4
        for (int d = 0; d < 64; ++d) {
            float qv = qrow[d], zv = zt[r][qd + d];
            double df = (double)qv - (double)zv;
            lacc += df * df;
            orow[d] = qv;
        }
    }
    for (int off = 32; off > 0; off >>= 1) lacc += __shfl_down(lacc, off, 64);
    if ((t & 63) == 0) lred[t >> 6] = lacc;
    __syncthreads();
    if (t == 0) partial[blockIdx.x] = lred[0] + lred[1] + lred[2] + lred[3];
}

// ============================ launch ============================

extern "C" void kernel_launch(void* const* d_in, const int* in_sizes, int n_in,
                              void* d_out, int out_size, void* d_ws, size_t ws_size,
                              hipStream_t stream) {
    const float* z = (const float*)d_in[0];
    const float* e = (const float*)d_in[1];
    float* out = (float*)d_out;
    char* w = (char*)d_ws;

    size_t o = 0;
    auto take = [&](size_t b) { size_t r = o; o = (o + b + 255) & ~(size_t)255; return r; };
    size_t o_zh = take((size_t)NROWS * DIM * 2);
    size_t o_eh = take((size_t)KCODES * DIM * 2);
    size_t o_cr = take((size_t)NROWS * 4);
    size_t o_eb = take((size_t)KCODES * 4);
    size_t o_tk = take((size_t)32 * NROWS * 4);
    size_t o_t2 = take((size_t)32 * NROWS * 4);
    size_t o_fk = take((size_t)NROWS * 8);
    size_t o_cn = take(512);
    size_t o_ls = take((size_t)128 * LCAP * 4);
    size_t o_pt = take((size_t)2048 * 8);
    size_t need = o;

    if (ws_size >= need) {
        ushort* zh = (ushort*)(w + o_zh);
        ushort* eh = (ushort*)(w + o_eh);
        float* Cr  = (float*)(w + o_cr);
        float* eb  = (float*)(w + o_eb);
        float* tk  = (float*)(w + o_tk);
        uint*  tk2 = (uint*)(w + o_t2);
        u64*   fk  = (u64*)(w + o_fk);
        int*   cn  = (int*)(w + o_cn);
        int*   ls  = (int*)(w + o_ls);
        double* pt = (double*)(w + o_pt);

        k_split<<<NROWS * DIM / 8 / 256, 256, 0, stream>>>(z, zh, NROWS * DIM / 8);
        k_split<<<KCODES * DIM / 8 / 256, 256, 0, stream>>>(e, eh, KCODES * DIM / 8);
        k_rownorm<<<NROWS / 256, 256, 0, stream>>>(z, Cr, NROWS);
        k_rownorm<<<KCODES / 256, 256, 0, stream>>>(e, eb, KCODES);
        k_init<<<1, 128, 0, stream>>>(cn);
        k_gemm<<<512 * 32, 256, 0, stream>>>(zh, eh, Cr, eb, tk, tk2);
        k_lists<<<NROWS / 256, 256, 0, stream>>>(tk, tk2, cn, ls, fk);
        dim3 ge(128, 16);
        k_exact<<<ge, 256, 0, stream>>>(z, e, Cr, eb, ls, cn, fk);
        k_gather<<<NROWS / 32, 256, 0, stream>>>(z, e, fk, out, pt);
        k_finish<<<1, 256, 0, stream>>>(pt, out, 2048);
    } else {
        float* Cr  = (float*)w;
        float* eb  = Cr + NROWS;
        double* pt = (double*)(eb + KCODES);
        k_rownorm<<<NROWS / 256, 256, 0, stream>>>(z, Cr, NROWS);
        k_rownorm<<<KCODES / 256, 256, 0, stream>>>(e, eb, KCODES);
        k_main_slow<<<NROWS / 64, 256, 0, stream>>>(z, e, Cr, eb, out, pt);
        k_finish<<<1, 256, 0, stream>>>(pt, out, NROWS / 64);
    }
}

// Round 7
// 519.886 us; speedup vs baseline: 11.7074x; 1.5739x over previous
//
#include <hip/hip_runtime.h>

#define KCODES 4096
#define DIM    256
#define NROWS  65536
#define MARGIN 4.0e-4f
#define DSLACK 3.0e-5f      // decode slack for u8-quantized subtile deltas
#define LCAP   4096         // per-subtile candidate list capacity (avg ~665)
#define LSTRIDE (DIM + 4)

typedef unsigned long long u64;
typedef unsigned int  uint;
typedef unsigned short ushort;
typedef __attribute__((ext_vector_type(8))) short bf16x8;
typedef __attribute__((ext_vector_type(4))) float f32x4;

typedef __attribute__((address_space(3))) uint lds_u32_t;
typedef __attribute__((address_space(1))) uint glb_u32_t;

__device__ __forceinline__ void g2lds16(const void* g, void* l) {
    __builtin_amdgcn_global_load_lds((const glb_u32_t*)g, (lds_u32_t*)l, 16, 0, 0);
}

// ============================ shared helpers ============================

__device__ __forceinline__ float np_half_sum128(const float4* __restrict__ p4) {
    #pragma clang fp contract(off)
    float4 v0 = p4[0], v1 = p4[1];
    float r0 = v0.x * v0.x, r1 = v0.y * v0.y, r2 = v0.z * v0.z, r3 = v0.w * v0.w;
    float r4 = v1.x * v1.x, r5 = v1.y * v1.y, r6 = v1.z * v1.z, r7 = v1.w * v1.w;
    #pragma unroll
    for (int i = 1; i < 16; ++i) {
        float4 a = p4[2 * i], b = p4[2 * i + 1];
        r0 += a.x * a.x; r1 += a.y * a.y; r2 += a.z * a.z; r3 += a.w * a.w;
        r4 += b.x * b.x; r5 += b.y * b.y; r6 += b.z * b.z; r7 += b.w * b.w;
    }
    return ((r0 + r1) + (r2 + r3)) + ((r4 + r5) + (r6 + r7));
}

__global__ void k_rownorm(const float* __restrict__ src, float* __restrict__ dst, int nrows) {
    int r = blockIdx.x * blockDim.x + threadIdx.x;
    if (r >= nrows) return;
    const float4* p4 = (const float4*)(src + (size_t)r * DIM);
    float s;
    {
        #pragma clang fp contract(off)
        s = np_half_sum128(p4) + np_half_sum128(p4 + 32);
    }
    dst[r] = s;
}

// validated (round 3): fl32( fl32(Cr+ebc) - fl32(2*fl32(cross_exact)) )
__device__ __forceinline__ float f32_dist(float Cr, float ebc, double accv) {
    #pragma clang fp contract(off)
    float A = Cr + ebc;
    float B = 2.0f * (float)accv;
    return A - B;
}

__device__ __forceinline__ ushort f2bf(float f) {
    uint u = __float_as_uint(f);
    return (ushort)((u + 0x7fffu + ((u >> 16) & 1u)) >> 16);
}

// ============================ fast-path kernels ============================

__global__ void k_split(const float* __restrict__ src, ushort* __restrict__ dst, int n8) {
    int i = blockIdx.x * blockDim.x + threadIdx.x;
    if (i >= n8) return;
    const float4* s4 = (const float4*)src;
    float4 a = s4[2 * i], b = s4[2 * i + 1];
    uint4 ov;
    ov.x = (uint)f2bf(a.x) | ((uint)f2bf(a.y) << 16);
    ov.y = (uint)f2bf(a.z) | ((uint)f2bf(a.w) << 16);
    ov.z = (uint)f2bf(b.x) | ((uint)f2bf(b.y) << 16);
    ov.w = (uint)f2bf(b.z) | ((uint)f2bf(b.w) << 16);
    *(uint4*)&dst[8 * i] = ov;
}

__global__ void k_init(int* __restrict__ cnt) {
    cnt[threadIdx.x] = 0;
}

// MFMA filter GEMM (m97 structure). Output per (row, 128-tile): tile-min f32
// + 4 per-32-code-subtile deltas (u8, quantum 1e-5, floor => conservative).
__global__ __launch_bounds__(256, 2)
void k_gemm(const ushort* __restrict__ zh, const ushort* __restrict__ eh,
            const float* __restrict__ Crow, const float* __restrict__ eb2,
            float* __restrict__ tk, uint* __restrict__ tk2) {
    __shared__ __align__(16) ushort smem[2][2][128 * 64];  // [buf][A=0/B=1][row*64+k]

    const int t = threadIdx.x;
    const int lane = t & 63;
    const int wv = t >> 6;
    const int wm = wv >> 1, wn = wv & 1;
    const int l15 = lane & 15, l4 = lane >> 4;
    const int bid = blockIdx.x;
    const int ct = bid & 31, rt = bid >> 5;
    const int row0 = rt * 128, col0 = ct * 128;

    f32x4 acc[4][4];
    #pragma unroll
    for (int i = 0; i < 4; ++i)
        #pragma unroll
        for (int j = 0; j < 4; ++j) acc[i][j] = (f32x4){0.f, 0.f, 0.f, 0.f};

    const char* zb = (const char*)zh;
    const char* ebp = (const char*)eh;

    auto stage = [&](int buf, int kt) {
        #pragma unroll
        for (int i = 0; i < 4; ++i) {
            int u = t + 256 * i;
            int r = u >> 3, c = u & 7;
            g2lds16(zb + ((size_t)(row0 + r) * 512 + kt * 128 + c * 16),
                    (char*)smem[buf][0] + u * 16);
            g2lds16(ebp + ((size_t)(col0 + r) * 512 + kt * 128 + c * 16),
                    (char*)smem[buf][1] + u * 16);
        }
    };

    stage(0, 0);
    __syncthreads();

    for (int kt = 0; kt < 4; ++kt) {
        int buf = kt & 1;
        if (kt < 3) stage(buf ^ 1, kt + 1);
        bf16x8 af[2][4], bfv[2][4];
        #pragma unroll
        for (int ks = 0; ks < 2; ++ks) {
            #pragma unroll
            for (int mi = 0; mi < 4; ++mi) {
                int rA = wm * 64 + mi * 16 + l15;
                af[ks][mi] = *(const bf16x8*)&smem[buf][0][rA * 64 + ks * 32 + l4 * 8];
            }
            #pragma unroll
            for (int ni = 0; ni < 4; ++ni) {
                int rB = wn * 64 + ni * 16 + l15;
                bfv[ks][ni] = *(const bf16x8*)&smem[buf][1][rB * 64 + ks * 32 + l4 * 8];
            }
        }
        #pragma unroll
        for (int ks = 0; ks < 2; ++ks)
            #pragma unroll
            for (int mi = 0; mi < 4; ++mi)
                #pragma unroll
                for (int ni = 0; ni < 4; ++ni)
                    acc[mi][ni] = __builtin_amdgcn_mfma_f32_16x16x32_bf16(
                        af[ks][mi], bfv[ks][ni], acc[mi][ni], 0, 0, 0);
        __syncthreads();
    }

    // ---- epilogue: per-(row, 32-code subtile) mins ----
    // D-frag (m89): col = lane&15, row = (lane>>4)*4 + reg.
    float* table = (float*)smem;   // 128*65*4 = 33.3 KB, safe after final barrier
    float eb[4];
    #pragma unroll
    for (int ni = 0; ni < 4; ++ni) eb[ni] = eb2[col0 + wn * 64 + ni * 16 + l15];

    #pragma unroll
    for (int mi = 0; mi < 4; ++mi) {
        #pragma unroll
        for (int rg = 0; rg < 4; ++rg) {
            int rloc = wm * 64 + mi * 16 + l4 * 4 + rg;
            float Cr = Crow[row0 + rloc];
            float d[4];
            #pragma unroll
            for (int ni = 0; ni < 4; ++ni) {
                #pragma clang fp contract(off)
                float A = Cr + eb[ni];
                d[ni] = A - 2.0f * acc[mi][ni][rg];
            }
            table[rloc * 65 + wn * 32 + l15]      = fminf(d[0], d[1]);
            table[rloc * 65 + wn * 32 + 16 + l15] = fminf(d[2], d[3]);
        }
    }
    __syncthreads();
    if (t < 128) {
        float m[4];
        #pragma unroll
        for (int p = 0; p < 4; ++p) {
            float v = table[t * 65 + p * 16];
            #pragma unroll
            for (int j = 1; j < 16; ++j) v = fminf(v, table[t * 65 + p * 16 + j]);
            m[p] = v;
        }
        float mt = fminf(fminf(m[0], m[1]), fminf(m[2], m[3]));
        uint pk = 0;
        #pragma unroll
        for (int p = 0; p < 4; ++p) {
            int q = (int)((m[p] - mt) * 1e5f);   // floor (nonneg) => decoded <= true
            q = q > 255 ? 255 : q;
            pk |= (uint)q << (8 * p);
        }
        tk [(size_t)ct * NROWS + row0 + t] = mt;
        tk2[(size_t)ct * NROWS + row0 + t] = pk;
    }
}

// per row: rowbest over 32 tile-mins; decode subtile mins; staggered sweep +
// wave-aggregated list append; init fkey. No per-thread arrays (no scratch);
// tk/tk2 re-loaded per tile-group (L1/L2-hot). Stagger kills atomic convoy.
__global__ void k_lists(const float* __restrict__ tk, const uint* __restrict__ tk2,
                        int* __restrict__ cnt, int* __restrict__ list,
                        u64* __restrict__ fkey) {
    int row = blockIdx.x * 256 + threadIdx.x;
    int lane = threadIdx.x & 63;
    float best = __int_as_float(0x7f800000);
    for (int tt = 0; tt < 32; ++tt)
        best = fminf(best, tk[(size_t)tt * NROWS + row]);
    fkey[row] = ~0ull;
    float cutoff = best + (MARGIN + DSLACK);

    int wid = (blockIdx.x << 2) | (threadIdx.x >> 6);
    int off = (wid * 13) & 31;      // per-wave staggered start tile
    for (int g = 0; g < 32; ++g) {
        int tt = (g + off) & 31;
        float tm = tk [(size_t)tt * NROWS + row];
        uint  pk = tk2[(size_t)tt * NROWS + row];
        #pragma unroll
        for (int p = 0; p < 4; ++p) {
            float v = tm + (float)((pk >> (8 * p)) & 255u) * 1e-5f;
            bool pred = v <= cutoff;
            u64 mask = __ballot(pred);
            if (mask) {
                int sub = tt * 4 + p;
                int nq = __popcll(mask);
                int rank = __popcll(mask & ((1ull << lane) - 1ull));
                int base = 0;
                if (lane == 0) base = atomicAdd(&cnt[sub], nq);
                base = __shfl(base, 0, 64);
                int pos = base + rank;
                if (pred && pos < LCAP) list[sub * LCAP + pos] = row;
            }
        }
    }
}

// exact decider per (subtile, row-chunk): e-subtile staged once per block,
// 32-row chunks, 2x2 register blocking. Validated f64-cross + f32_dist +
// lexicographic (d,idx) key, atomicMin-merged.
__global__ __launch_bounds__(256, 2)
void k_exact(const float* __restrict__ z, const float* __restrict__ e,
             const float* __restrict__ Crow, const float* __restrict__ eb2,
             const int* __restrict__ list, const int* __restrict__ cnt,
             u64* __restrict__ fkey) {
    __shared__ __align__(16) float ex[32][260];
    __shared__ __align__(16) float zx[32][260];
    __shared__ int rows[32];
    __shared__ u64 keytab[32][17];
    const int sub = blockIdx.x;       // 0..127
    const int nct = cnt[sub];
    const int t = threadIdx.x;
    const int rp = t & 15, cq = t >> 4;

    {   // stage e subtile (32 codes x 256) once; covered by first loop barrier
        int cc = t >> 3, c8 = t & 7;
        const float4* src = (const float4*)(e + (size_t)(sub * 32 + cc) * DIM);
        float4* dr = (float4*)ex[cc];
        #pragma unroll
        for (int j = 0; j < 8; ++j) dr[c8 + 8 * j] = src[c8 + 8 * j];
    }
    const float ebc0 = eb2[sub * 32 + cq];
    const float ebc1 = eb2[sub * 32 + 16 + cq];
    const int c0 = sub * 32 + cq, c1 = sub * 32 + 16 + cq;

    for (int base = blockIdx.y * 32; base < nct; base += gridDim.y * 32) {
        __syncthreads();   // prior iter's keytab/rows reads done; e-stage done
        if (t < 32) {
            int i = base + t;
            rows[t] = list[sub * LCAP + (i < nct ? i : nct - 1)];
        }
        __syncthreads();
        {   // stage 32 z rows
            int rr = t >> 3, c8 = t & 7;
            const float4* src = (const float4*)(z + (size_t)rows[rr] * DIM);
            float4* dr = (float4*)zx[rr];
            #pragma unroll
            for (int j = 0; j < 8; ++j) dr[c8 + 8 * j] = src[c8 + 8 * j];
        }
        __syncthreads();

        double a00 = 0.0, a01 = 0.0, a10 = 0.0, a11 = 0.0;
        const float4* z0 = (const float4*)zx[rp];
        const float4* z1 = (const float4*)zx[rp + 16];
        const float4* e0 = (const float4*)ex[cq];
        const float4* e1 = (const float4*)ex[cq + 16];
        #pragma unroll 8
        for (int d4 = 0; d4 < 64; ++d4) {
            float4 x0 = z0[d4], x1 = z1[d4], y0 = e0[d4], y1 = e1[d4];
            a00 += (double)x0.x * (double)y0.x; a00 += (double)x0.y * (double)y0.y;
            a00 += (double)x0.z * (double)y0.z; a00 += (double)x0.w * (double)y0.w;
            a01 += (double)x0.x * (double)y1.x; a01 += (double)x0.y * (double)y1.y;
            a01 += (double)x0.z * (double)y1.z; a01 += (double)x0.w * (double)y1.w;
            a10 += (double)x1.x * (double)y0.x; a10 += (double)x1.y * (double)y0.y;
            a10 += (double)x1.z * (double)y0.z; a10 += (double)x1.w * (double)y0.w;
            a11 += (double)x1.x * (double)y1.x; a11 += (double)x1.y * (double)y1.y;
            a11 += (double)x1.z * (double)y1.z; a11 += (double)x1.w * (double)y1.w;
        }
        int r0 = rows[rp], r1 = rows[rp + 16];
        float C0 = Crow[r0], C1 = Crow[r1];
        u64 k00 = ((u64)__float_as_uint(f32_dist(C0, ebc0, a00)) << 32) | (u64)c0;
        u64 k01 = ((u64)__float_as_uint(f32_dist(C0, ebc1, a01)) << 32) | (u64)c1;
        u64 k10 = ((u64)__float_as_uint(f32_dist(C1, ebc0, a10)) << 32) | (u64)c0;
        u64 k11 = ((u64)__float_as_uint(f32_dist(C1, ebc1, a11)) << 32) | (u64)c1;
        keytab[rp][cq]      = k00 < k01 ? k00 : k01;
        keytab[rp + 16][cq] = k10 < k11 ? k10 : k11;
        __syncthreads();
        if (t < 32) {
            u64 kb = keytab[t][0];
            #pragma unroll
            for (int j = 1; j < 16; ++j) {
                u64 k = keytab[t][j];
                kb = k < kb ? k : kb;
            }
            atomicMin((unsigned long long*)&fkey[rows[t]], kb);
        }
    }
}

__global__ __launch_bounds__(256)
void k_gather(const float* __restrict__ z, const float* __restrict__ e,
              const u64* __restrict__ fkey, float* __restrict__ out,
              double* __restrict__ partial) {
    __shared__ double lred[4];
    const int t = threadIdx.x;
    const int row = blockIdx.x * 32 + (t >> 3);
    const int c8 = t & 7;
    const int idx = (int)(fkey[row] & 0xffffffffull);
    if (c8 == 0) out[1 + (size_t)NROWS * DIM + row] = (float)idx;
    const float4* zr = (const float4*)(z + (size_t)row * DIM);
    const float4* er = (const float4*)(e + (size_t)idx * DIM);
    float4* orow = (float4*)(out + 1 + (size_t)row * DIM);
    double lacc = 0.0;
    #pragma unroll
    for (int j = 0; j < 8; ++j) {
        float4 q = er[c8 + 8 * j];
        float4 zv = zr[c8 + 8 * j];
        orow[c8 + 8 * j] = q;
        double d0 = (double)q.x - (double)zv.x;
        double d1 = (double)q.y - (double)zv.y;
        double d2 = (double)q.z - (double)zv.z;
        double d3 = (double)q.w - (double)zv.w;
        lacc += d0 * d0 + d1 * d1 + d2 * d2 + d3 * d3;
    }
    for (int off = 32; off > 0; off >>= 1) lacc += __shfl_down(lacc, off, 64);
    if ((t & 63) == 0) lred[t >> 6] = lacc;
    __syncthreads();
    if (t == 0) partial[blockIdx.x] = lred[0] + lred[1] + lred[2] + lred[3];
}

__global__ void k_finish(const double* __restrict__ partial, float* __restrict__ out, int n) {
    __shared__ double s[256];
    double a = 0.0;
    for (int i = threadIdx.x; i < n; i += 256) a += partial[i];
    s[threadIdx.x] = a;
    __syncthreads();
    for (int off = 128; off > 0; off >>= 1) {
        if (threadIdx.x < off) s[threadIdx.x] += s[threadIdx.x + off];
        __syncthreads();
    }
    if (threadIdx.x == 0)
        out[0] = (float)(1.25 * s[0] / ((double)NROWS * (double)DIM));
}

// ===================== fallback (round-3 validated path) =====================

__global__ __launch_bounds__(256, 1)
void k_main_slow(const float* __restrict__ z, const float* __restrict__ e,
                 const float* __restrict__ Crow, const float* __restrict__ eb2,
                 float* __restrict__ out, double* __restrict__ partial) {
    __shared__ float  zt[64][LSTRIDE];
    __shared__ float  et[64][LSTRIDE];
    __shared__ float  redd[64][17];
    __shared__ int    redi[64][17];
    __shared__ int    bsel[64];
    __shared__ double lred[4];

    const int t  = threadIdx.x;
    const int tx = t & 15;
    const int ty = t >> 4;
    const int row0 = blockIdx.x * 64;

    {
        const float4* zsrc = (const float4*)(z + (size_t)row0 * DIM);
        for (int i = t; i < 64 * (DIM / 4); i += 256) {
            int r = i >> 6, c4 = i & 63;
            *(float4*)&zt[r][c4 * 4] = zsrc[r * (DIM / 4) + c4];
        }
    }
    float Cr[4];
    #pragma unroll
    for (int ri = 0; ri < 4; ++ri) Cr[ri] = Crow[row0 + ty * 4 + ri];
    float bestd[4]; int besti[4];
    #pragma unroll
    for (int ri = 0; ri < 4; ++ri) { bestd[ri] = __int_as_float(0x7f800000); besti[ri] = 0; }

    for (int kt = 0; kt < KCODES / 64; ++kt) {
        __syncthreads();
        {
            const float4* esrc = (const float4*)(e + (size_t)kt * 64 * DIM);
            for (int i = t; i < 64 * (DIM / 4); i += 256) {
                int r = i >> 6, c4 = i & 63;
                *(float4*)&et[r][c4 * 4] = esrc[r * (DIM / 4) + c4];
            }
        }
        __syncthreads();
        double acc[4][4];
        #pragma unroll
        for (int a = 0; a < 4; ++a)
            #pragma unroll
            for (int b = 0; b < 4; ++b) acc[a][b] = 0.0;
        #pragma unroll 4
        for (int d4 = 0; d4 < DIM / 4; ++d4) {
            float4 za[4], ea[4];
            #pragma unroll
            for (int ri = 0; ri < 4; ++ri) za[ri] = *(const float4*)&zt[ty * 4 + ri][d4 * 4];
            #pragma unroll
            for (int ci = 0; ci < 4; ++ci) ea[ci] = *(const float4*)&et[tx + 16 * ci][d4 * 4];
            #pragma unroll
            for (int ri = 0; ri < 4; ++ri)
                #pragma unroll
                for (int ci = 0; ci < 4; ++ci)
                    acc[ri][ci] += (double)za[ri].x * (double)ea[ci].x
                                 + (double)za[ri].y * (double)ea[ci].y
                                 + (double)za[ri].z * (double)ea[ci].z
                                 + (double)za[ri].w * (double)ea[ci].w;
        }
        #pragma unroll
        for (int ci = 0; ci < 4; ++ci) {
            int c = kt * 64 + tx + 16 * ci;
            float ebc = eb2[c];
            #pragma unroll
            for (int ri = 0; ri < 4; ++ri) {
                float d = f32_dist(Cr[ri], ebc, acc[ri][ci]);
                if (d < bestd[ri]) { bestd[ri] = d; besti[ri] = c; }
            }
        }
    }
    __syncthreads();
    #pragma unroll
    for (int ri = 0; ri < 4; ++ri) {
        redd[ty * 4 + ri][tx] = bestd[ri];
        redi[ty * 4 + ri][tx] = besti[ri];
    }
    __syncthreads();
    if (t < 64) {
        float bd = redd[t][0]; int bi = redi[t][0];
        for (int j = 1; j < 16; ++j) {
            float d = redd[t][j]; int i2 = redi[t][j];
            if (d < bd || (d == bd && i2 < bi)) { bd = d; bi = i2; }
        }
        bsel[t] = bi;
        out[1 + (size_t)NROWS * DIM + row0 + t] = (float)bi;
    }
    __syncthreads();
    double lacc = 0.0;
    {
        int r = t >> 2, qd = (t & 3) * 64;
        int bi = bsel[r];
        const float* qrow = e + (size_t)bi * DIM + qd;
        float* orow = out + 1 + (size_t)(row0 + r) * DIM + qd;
        #pragma unroll 4
        for (int d = 0; d < 64; ++d) {
            float qv = qrow[d], zv = zt[r][qd + d];
            double df = (double)qv - (double)zv;
            lacc += df * df;
            orow[d] = qv;
        }
    }
    for (int off = 32; off > 0; off >>= 1) lacc += __shfl_down(lacc, off, 64);
    if ((t & 63) == 0) lred[t >> 6] = lacc;
    __syncthreads();
    if (t == 0) partial[blockIdx.x] = lred[0] + lred[1] + lred[2] + lred[3];
}

// ============================ launch ============================

extern "C" void kernel_launch(void* const* d_in, const int* in_sizes, int n_in,
                              void* d_out, int out_size, void* d_ws, size_t ws_size,
                              hipStream_t stream) {
    const float* z = (const float*)d_in[0];
    const float* e = (const float*)d_in[1];
    float* out = (float*)d_out;
    char* w = (char*)d_ws;

    size_t o = 0;
    auto take = [&](size_t b) { size_t r = o; o = (o + b + 255) & ~(size_t)255; return r; };
    size_t o_zh = take((size_t)NROWS * DIM * 2);
    size_t o_eh = take((size_t)KCODES * DIM * 2);
    size_t o_cr = take((size_t)NROWS * 4);
    size_t o_eb = take((size_t)KCODES * 4);
    size_t o_tk = take((size_t)32 * NROWS * 4);
    size_t o_t2 = take((size_t)32 * NROWS * 4);
    size_t o_fk = take((size_t)NROWS * 8);
    size_t o_cn = take(512);
    size_t o_ls = take((size_t)128 * LCAP * 4);
    size_t o_pt = take((size_t)2048 * 8);
    size_t need = o;

    if (ws_size >= need) {
        ushort* zh = (ushort*)(w + o_zh);
        ushort* eh = (ushort*)(w + o_eh);
        float* Cr  = (float*)(w + o_cr);
        float* eb  = (float*)(w + o_eb);
        float* tk  = (float*)(w + o_tk);
        uint*  tk2 = (uint*)(w + o_t2);
        u64*   fk  = (u64*)(w + o_fk);
        int*   cn  = (int*)(w + o_cn);
        int*   ls  = (int*)(w + o_ls);
        double* pt = (double*)(w + o_pt);

        k_split<<<NROWS * DIM / 8 / 256, 256, 0, stream>>>(z, zh, NROWS * DIM / 8);
        k_split<<<KCODES * DIM / 8 / 256, 256, 0, stream>>>(e, eh, KCODES * DIM / 8);
        k_rownorm<<<NROWS / 256, 256, 0, stream>>>(z, Cr, NROWS);
        k_rownorm<<<KCODES / 256, 256, 0, stream>>>(e, eb, KCODES);
        k_init<<<1, 128, 0, stream>>>(cn);
        k_gemm<<<512 * 32, 256, 0, stream>>>(zh, eh, Cr, eb, tk, tk2);
        k_lists<<<NROWS / 256, 256, 0, stream>>>(tk, tk2, cn, ls, fk);
        dim3 ge(128, 16);
        k_exact<<<ge, 256, 0, stream>>>(z, e, Cr, eb, ls, cn, fk);
        k_gather<<<NROWS / 32, 256, 0, stream>>>(z, e, fk, out, pt);
        k_finish<<<1, 256, 0, stream>>>(pt, out, 2048);
    } else {
        float* Cr  = (float*)w;
        float* eb  = Cr + NROWS;
        double* pt = (double*)(eb + KCODES);
        k_rownorm<<<NROWS / 256, 256, 0, stream>>>(z, Cr, NROWS);
        k_rownorm<<<KCODES / 256, 256, 0, stream>>>(e, eb, KCODES);
        k_main_slow<<<NROWS / 64, 256, 0, stream>>>(z, e, Cr, eb, out, pt);
        k_finish<<<1, 256, 0, stream>>>(pt, out, NROWS / 64);
    }
}

// Round 8
// 483.400 us; speedup vs baseline: 12.5911x; 1.0755x over previous
//
#include <hip/hip_runtime.h>

#define KCODES 4096
#define DIM    256
#define NROWS  65536
#define MARGIN 4.0e-4f
#define DSLACK 3.0e-5f
#define LCAP   4096
#define LSTRIDE (DIM + 4)

typedef unsigned long long u64;
typedef unsigned int  uint;
typedef unsigned short ushort;
typedef __attribute__((ext_vector_type(8))) short bf16x8;
typedef __attribute__((ext_vector_type(4))) float f32x4;

typedef __attribute__((address_space(3))) uint lds_u32_t;
typedef __attribute__((address_space(1))) uint glb_u32_t;

__device__ __forceinline__ void g2lds16(const void* g, void* l) {
    __builtin_amdgcn_global_load_lds((const glb_u32_t*)g, (lds_u32_t*)l, 16, 0, 0);
}

// lane-min across quad (l15&3) then tile via row_ror — DPP, VALU pipe
__device__ __forceinline__ float dppmin_quad(float m) {
    m = fminf(m, __int_as_float(__builtin_amdgcn_update_dpp(0, __float_as_int(m), 0xB1, 0xF, 0xF, true)));
    m = fminf(m, __int_as_float(__builtin_amdgcn_update_dpp(0, __float_as_int(m), 0x4E, 0xF, 0xF, true)));
    return m;
}
__device__ __forceinline__ float dppmin_row16(float m) {
    m = fminf(m, __int_as_float(__builtin_amdgcn_update_dpp(0, __float_as_int(m), 0x124, 0xF, 0xF, true)));
    m = fminf(m, __int_as_float(__builtin_amdgcn_update_dpp(0, __float_as_int(m), 0x128, 0xF, 0xF, true)));
    return m;
}
__device__ __forceinline__ uint dppor_row16(uint v) {
    v |= (uint)__builtin_amdgcn_update_dpp(0, (int)v, 0x124, 0xF, 0xF, true);
    v |= (uint)__builtin_amdgcn_update_dpp(0, (int)v, 0x128, 0xF, 0xF, true);
    return v;
}

// ============================ shared helpers ============================

__device__ __forceinline__ float np_half_sum128(const float4* __restrict__ p4) {
    #pragma clang fp contract(off)
    float4 v0 = p4[0], v1 = p4[1];
    float r0 = v0.x * v0.x, r1 = v0.y * v0.y, r2 = v0.z * v0.z, r3 = v0.w * v0.w;
    float r4 = v1.x * v1.x, r5 = v1.y * v1.y, r6 = v1.z * v1.z, r7 = v1.w * v1.w;
    #pragma unroll
    for (int i = 1; i < 16; ++i) {
        float4 a = p4[2 * i], b = p4[2 * i + 1];
        r0 += a.x * a.x; r1 += a.y * a.y; r2 += a.z * a.z; r3 += a.w * a.w;
        r4 += b.x * b.x; r5 += b.y * b.y; r6 += b.z * b.z; r7 += b.w * b.w;
    }
    return ((r0 + r1) + (r2 + r3)) + ((r4 + r5) + (r6 + r7));
}

__global__ void k_rownorm(const float* __restrict__ src, float* __restrict__ dst, int nrows) {
    int r = blockIdx.x * blockDim.x + threadIdx.x;
    if (r >= nrows) return;
    const float4* p4 = (const float4*)(src + (size_t)r * DIM);
    float s;
    {
        #pragma clang fp contract(off)
        s = np_half_sum128(p4) + np_half_sum128(p4 + 32);
    }
    dst[r] = s;
}

// validated (round 3): fl32( fl32(Cr+ebc) - fl32(2*fl32(cross_exact)) )
__device__ __forceinline__ float f32_dist(float Cr, float ebc, double accv) {
    #pragma clang fp contract(off)
    float A = Cr + ebc;
    float B = 2.0f * (float)accv;
    return A - B;
}

__device__ __forceinline__ ushort f2bf(float f) {
    uint u = __float_as_uint(f);
    return (ushort)((u + 0x7fffu + ((u >> 16) & 1u)) >> 16);
}

// ============================ fast-path kernels ============================

__global__ void k_split(const float* __restrict__ src, ushort* __restrict__ dst, int n8) {
    int i = blockIdx.x * blockDim.x + threadIdx.x;
    if (i >= n8) return;
    const float4* s4 = (const float4*)src;
    float4 a = s4[2 * i], b = s4[2 * i + 1];
    uint4 ov;
    ov.x = (uint)f2bf(a.x) | ((uint)f2bf(a.y) << 16);
    ov.y = (uint)f2bf(a.z) | ((uint)f2bf(a.w) << 16);
    ov.z = (uint)f2bf(b.x) | ((uint)f2bf(b.y) << 16);
    ov.w = (uint)f2bf(b.z) | ((uint)f2bf(b.w) << 16);
    *(uint4*)&dst[8 * i] = ov;
}

__global__ void k_init(int* __restrict__ cnt) {
    cnt[threadIdx.x] = 0;
}

// MFMA filter: z in registers (64 rows/wave, full K), e streamed via swizzled
// LDS tiles (128 codes, dbuf). Subtile p = l15-quad: codes {cg*16+p*4+r}.
// Output per (row, 128-tile): tile-min f32 + 4 u8 quad-subtile deltas.
__global__ __launch_bounds__(256, 1)
void k_gemm(const ushort* __restrict__ zh, const ushort* __restrict__ eh,
            const float* __restrict__ Crow, const float* __restrict__ eb2,
            float* __restrict__ tk, uint* __restrict__ tk2) {
    __shared__ __align__(16) ushort Bs[2][128 * 256];   // 2 x 64KB

    const int t = threadIdx.x;
    const int lane = t & 63;
    const int w = t >> 6;               // wave 0..3
    const int l15 = lane & 15, l4 = lane >> 4;
    const int row0w = blockIdx.x * 256 + w * 64;

    const char* ebp = (const char*)eh;

    // stage e-tile ct2 into Bs[buf]: linear LDS dest, inverse-swizzled source
    // (chunk c16 within 512B row swapped by code&7) so swizzled READ is clean.
    auto stage = [&](int buf, int ct2) {
        const char* base = ebp + (size_t)ct2 * 128 * 512;
        #pragma unroll
        for (int i = 0; i < 16; ++i) {
            int idx = i * 256 + t;            // 0..4095 16B-chunks
            int code = idx >> 5;
            int c16  = idx & 31;
            int src  = (code << 9) + ((c16 ^ (code & 7)) << 4);
            g2lds16(base + src, (char*)Bs[buf] + idx * 16);
        }
    };

    // ---- A: 64 rows x 256 K in registers (layout = MFMA A-frag) ----
    bf16x8 a[4][8];
    #pragma unroll
    for (int f = 0; f < 4; ++f)
        #pragma unroll
        for (int ks = 0; ks < 8; ++ks)
            a[f][ks] = *(const bf16x8*)&zh[(size_t)(row0w + f * 16 + l15) * 256 + ks * 32 + l4 * 8];

    float crf[16];
    #pragma unroll
    for (int f = 0; f < 4; ++f)
        #pragma unroll
        for (int rg = 0; rg < 4; ++rg)
            crf[f * 4 + rg] = Crow[row0w + f * 16 + l4 * 4 + rg];

    stage(0, 0);
    __syncthreads();

    for (int ct = 0; ct < 32; ++ct) {
        int buf = ct & 1;
        if (ct < 31) stage(buf ^ 1, ct + 1);

        f32x4 acc[4][8];
        #pragma unroll
        for (int f = 0; f < 4; ++f)
            #pragma unroll
            for (int cg = 0; cg < 8; ++cg) acc[f][cg] = (f32x4){0.f, 0.f, 0.f, 0.f};

        const ushort* Bb = Bs[buf];
        #pragma unroll
        for (int ks = 0; ks < 8; ++ks) {
            bf16x8 bfv[8];
            #pragma unroll
            for (int cg = 0; cg < 8; ++cg) {
                int rB = cg * 16 + l15;
                int off = rB * 256 + ((ks * 32 + l4 * 8) ^ ((l15 & 7) << 3));
                bfv[cg] = *(const bf16x8*)&Bb[off];
            }
            #pragma unroll
            for (int f = 0; f < 4; ++f)
                #pragma unroll
                for (int cg = 0; cg < 8; ++cg)
                    acc[f][cg] = __builtin_amdgcn_mfma_f32_16x16x32_bf16(
                        a[f][ks], bfv[cg], acc[f][cg], 0, 0, 0);
        }

        // ---- epilogue: per-row quad-subtile mins, all cross-lane via DPP ----
        float ebv[8];
        #pragma unroll
        for (int cg = 0; cg < 8; ++cg) ebv[cg] = eb2[ct * 128 + cg * 16 + l15];

        #pragma unroll
        for (int f = 0; f < 4; ++f) {
            #pragma unroll
            for (int rg = 0; rg < 4; ++rg) {
                float m;
                {
                    #pragma clang fp contract(off)
                    m = 1e38f;
                    #pragma unroll
                    for (int cg = 0; cg < 8; ++cg) {
                        float A = crf[f * 4 + rg] + ebv[cg];
                        float d = A - 2.0f * acc[f][cg][rg];
                        m = fminf(m, d);
                    }
                }
                m = dppmin_quad(m);          // subtile (l15>>2) min
                float mt = dppmin_row16(m);  // tile min
                int q = (int)((m - mt) * 1e5f);
                q = q > 255 ? 255 : q;
                uint pk = (uint)q << (8 * (l15 >> 2));
                pk = dppor_row16(pk);
                if (l15 == 0) {
                    int grow = row0w + f * 16 + l4 * 4 + rg;
                    tk [(size_t)ct * NROWS + grow] = mt;
                    tk2[(size_t)ct * NROWS + grow] = pk;
                }
            }
        }
        __syncthreads();
    }
}

// per row: rowbest over 32 tile-mins; decode subtile mins; staggered sweep +
// wave-aggregated list append; init fkey.
__global__ void k_lists(const float* __restrict__ tk, const uint* __restrict__ tk2,
                        int* __restrict__ cnt, int* __restrict__ list,
                        u64* __restrict__ fkey) {
    int row = blockIdx.x * 256 + threadIdx.x;
    int lane = threadIdx.x & 63;
    float best = __int_as_float(0x7f800000);
    for (int tt = 0; tt < 32; ++tt)
        best = fminf(best, tk[(size_t)tt * NROWS + row]);
    fkey[row] = ~0ull;
    float cutoff = best + (MARGIN + DSLACK);

    int wid = (blockIdx.x << 2) | (threadIdx.x >> 6);
    int off = (wid * 13) & 31;
    for (int g = 0; g < 32; ++g) {
        int tt = (g + off) & 31;
        float tm = tk [(size_t)tt * NROWS + row];
        uint  pk = tk2[(size_t)tt * NROWS + row];
        #pragma unroll
        for (int p = 0; p < 4; ++p) {
            float v = tm + (float)((pk >> (8 * p)) & 255u) * 1e-5f;
            bool pred = v <= cutoff;
            u64 mask = __ballot(pred);
            if (mask) {
                int sub = tt * 4 + p;
                int nq = __popcll(mask);
                int rank = __popcll(mask & ((1ull << lane) - 1ull));
                int base = 0;
                if (lane == 0) base = atomicAdd(&cnt[sub], nq);
                base = __shfl(base, 0, 64);
                int pos = base + rank;
                if (pred && pos < LCAP) list[sub * LCAP + pos] = row;
            }
        }
    }
}

// exact decider; subtile sub = (tile<<2)|quad: codes = tile*128+cg*16+quad*4+r.
// Validated f64-cross + f32_dist + lexicographic (d,idx) key, atomicMin-merged.
__global__ __launch_bounds__(256, 2)
void k_exact(const float* __restrict__ z, const float* __restrict__ e,
             const float* __restrict__ Crow, const float* __restrict__ eb2,
             const int* __restrict__ list, const int* __restrict__ cnt,
             u64* __restrict__ fkey) {
    __shared__ __align__(16) float ex[32][260];
    __shared__ __align__(16) float zx[32][260];
    __shared__ int rows[32];
    __shared__ u64 keytab[32][17];
    const int sub = blockIdx.x;       // 0..127
    const int tile = sub >> 2, qq = sub & 3;
    const int nct = cnt[sub];
    const int t = threadIdx.x;
    const int rp = t & 15, cs = t >> 4;

    {   // stage e subtile (32 quad-mapped codes x 256)
        int cc = t >> 3, c8 = t & 7;
        int gcode = tile * 128 + (cc >> 2) * 16 + qq * 4 + (cc & 3);
        const float4* src = (const float4*)(e + (size_t)gcode * DIM);
        float4* dr = (float4*)ex[cc];
        #pragma unroll
        for (int j = 0; j < 8; ++j) dr[c8 + 8 * j] = src[c8 + 8 * j];
    }
    const int gc0 = tile * 128 + (cs >> 2) * 16 + qq * 4 + (cs & 3);
    const int gc1 = tile * 128 + ((cs >> 2) + 4) * 16 + qq * 4 + (cs & 3);
    const float ebc0 = eb2[gc0];
    const float ebc1 = eb2[gc1];

    for (int base = blockIdx.y * 32; base < nct; base += gridDim.y * 32) {
        __syncthreads();
        if (t < 32) {
            int i = base + t;
            rows[t] = list[sub * LCAP + (i < nct ? i : nct - 1)];
        }
        __syncthreads();
        {
            int rr = t >> 3, c8 = t & 7;
            const float4* src = (const float4*)(z + (size_t)rows[rr] * DIM);
            float4* dr = (float4*)zx[rr];
            #pragma unroll
            for (int j = 0; j < 8; ++j) dr[c8 + 8 * j] = src[c8 + 8 * j];
        }
        __syncthreads();

        double a00 = 0.0, a01 = 0.0, a10 = 0.0, a11 = 0.0;
        const float4* z0 = (const float4*)zx[rp];
        const float4* z1 = (const float4*)zx[rp + 16];
        const float4* e0 = (const float4*)ex[cs];
        const float4* e1 = (const float4*)ex[cs + 16];
        #pragma unroll 8
        for (int d4 = 0; d4 < 64; ++d4) {
            float4 x0 = z0[d4], x1 = z1[d4], y0 = e0[d4], y1 = e1[d4];
            a00 += (double)x0.x * (double)y0.x; a00 += (double)x0.y * (double)y0.y;
            a00 += (double)x0.z * (double)y0.z; a00 += (double)x0.w * (double)y0.w;
            a01 += (double)x0.x * (double)y1.x; a01 += (double)x0.y * (double)y1.y;
            a01 += (double)x0.z * (double)y1.z; a01 += (double)x0.w * (double)y1.w;
            a10 += (double)x1.x * (double)y0.x; a10 += (double)x1.y * (double)y0.y;
            a10 += (double)x1.z * (double)y0.z; a10 += (double)x1.w * (double)y0.w;
            a11 += (double)x1.x * (double)y1.x; a11 += (double)x1.y * (double)y1.y;
            a11 += (double)x1.z * (double)y1.z; a11 += (double)x1.w * (double)y1.w;
        }
        int r0 = rows[rp], r1 = rows[rp + 16];
        float C0 = Crow[r0], C1 = Crow[r1];
        u64 k00 = ((u64)__float_as_uint(f32_dist(C0, ebc0, a00)) << 32) | (u64)gc0;
        u64 k01 = ((u64)__float_as_uint(f32_dist(C0, ebc1, a01)) << 32) | (u64)gc1;
        u64 k10 = ((u64)__float_as_uint(f32_dist(C1, ebc0, a10)) << 32) | (u64)gc0;
        u64 k11 = ((u64)__float_as_uint(f32_dist(C1, ebc1, a11)) << 32) | (u64)gc1;
        keytab[rp][cs]      = k00 < k01 ? k00 : k01;
        keytab[rp + 16][cs] = k10 < k11 ? k10 : k11;
        __syncthreads();
        if (t < 32) {
            u64 kb = keytab[t][0];
            #pragma unroll
            for (int j = 1; j < 16; ++j) {
                u64 k = keytab[t][j];
                kb = k < kb ? k : kb;
            }
            atomicMin((unsigned long long*)&fkey[rows[t]], kb);
        }
    }
}

__global__ __launch_bounds__(256)
void k_gather(const float* __restrict__ z, const float* __restrict__ e,
              const u64* __restrict__ fkey, float* __restrict__ out,
              double* __restrict__ partial) {
    __shared__ double lred[4];
    const int t = threadIdx.x;
    const int row = blockIdx.x * 32 + (t >> 3);
    const int c8 = t & 7;
    const int idx = (int)(fkey[row] & 0xffffffffull);
    if (c8 == 0) out[1 + (size_t)NROWS * DIM + row] = (float)idx;
    const float4* zr = (const float4*)(z + (size_t)row * DIM);
    const float4* er = (const float4*)(e + (size_t)idx * DIM);
    float4* orow = (float4*)(out + 1 + (size_t)row * DIM);
    double lacc = 0.0;
    #pragma unroll
    for (int j = 0; j < 8; ++j) {
        float4 q = er[c8 + 8 * j];
        float4 zv = zr[c8 + 8 * j];
        orow[c8 + 8 * j] = q;
        double d0 = (double)q.x - (double)zv.x;
        double d1 = (double)q.y - (double)zv.y;
        double d2 = (double)q.z - (double)zv.z;
        double d3 = (double)q.w - (double)zv.w;
        lacc += d0 * d0 + d1 * d1 + d2 * d2 + d3 * d3;
    }
    for (int off = 32; off > 0; off >>= 1) lacc += __shfl_down(lacc, off, 64);
    if ((t & 63) == 0) lred[t >> 6] = lacc;
    __syncthreads();
    if (t == 0) partial[blockIdx.x] = lred[0] + lred[1] + lred[2] + lred[3];
}

__global__ void k_finish(const double* __restrict__ partial, float* __restrict__ out, int n) {
    __shared__ double s[256];
    double a = 0.0;
    for (int i = threadIdx.x; i < n; i += 256) a += partial[i];
    s[threadIdx.x] = a;
    __syncthreads();
    for (int off = 128; off > 0; off >>= 1) {
        if (threadIdx.x < off) s[threadIdx.x] += s[threadIdx.x + off];
        __syncthreads();
    }
    if (threadIdx.x == 0)
        out[0] = (float)(1.25 * s[0] / ((double)NROWS * (double)DIM));
}

// ===================== fallback (round-3 validated path) =====================

__global__ __launch_bounds__(256, 1)
void k_main_slow(const float* __restrict__ z, const float* __restrict__ e,
                 const float* __restrict__ Crow, const float* __restrict__ eb2,
                 float* __restrict__ out, double* __restrict__ partial) {
    __shared__ float  zt[64][LSTRIDE];
    __shared__ float  et[64][LSTRIDE];
    __shared__ float  redd[64][17];
    __shared__ int    redi[64][17];
    __shared__ int    bsel[64];
    __shared__ double lred[4];

    const int t  = threadIdx.x;
    const int tx = t & 15;
    const int ty = t >> 4;
    const int row0 = blockIdx.x * 64;

    {
        const float4* zsrc = (const float4*)(z + (size_t)row0 * DIM);
        for (int i = t; i < 64 * (DIM / 4); i += 256) {
            int r = i >> 6, c4 = i & 63;
            *(float4*)&zt[r][c4 * 4] = zsrc[r * (DIM / 4) + c4];
        }
    }
    float Cr[4];
    #pragma unroll
    for (int ri = 0; ri < 4; ++ri) Cr[ri] = Crow[row0 + ty * 4 + ri];
    float bestd[4]; int besti[4];
    #pragma unroll
    for (int ri = 0; ri < 4; ++ri) { bestd[ri] = __int_as_float(0x7f800000); besti[ri] = 0; }

    for (int kt = 0; kt < KCODES / 64; ++kt) {
        __syncthreads();
        {
            const float4* esrc = (const float4*)(e + (size_t)kt * 64 * DIM);
            for (int i = t; i < 64 * (DIM / 4); i += 256) {
                int r = i >> 6, c4 = i & 63;
                *(float4*)&et[r][c4 * 4] = esrc[r * (DIM / 4) + c4];
            }
        }
        __syncthreads();
        double acc[4][4];
        #pragma unroll
        for (int a = 0; a < 4; ++a)
            #pragma unroll
            for (int b = 0; b < 4; ++b) acc[a][b] = 0.0;
        #pragma unroll 4
        for (int d4 = 0; d4 < DIM / 4; ++d4) {
            float4 za[4], ea[4];
            #pragma unroll
            for (int ri = 0; ri < 4; ++ri) za[ri] = *(const float4*)&zt[ty * 4 + ri][d4 * 4];
            #pragma unroll
            for (int ci = 0; ci < 4; ++ci) ea[ci] = *(const float4*)&et[tx + 16 * ci][d4 * 4];
            #pragma unroll
            for (int ri = 0; ri < 4; ++ri)
                #pragma unroll
                for (int ci = 0; ci < 4; ++ci)
                    acc[ri][ci] += (double)za[ri].x * (double)ea[ci].x
                                 + (double)za[ri].y * (double)ea[ci].y
                                 + (double)za[ri].z * (double)ea[ci].z
                                 + (double)za[ri].w * (double)ea[ci].w;
        }
        #pragma unroll
        for (int ci = 0; ci < 4; ++ci) {
            int c = kt * 64 + tx + 16 * ci;
            float ebc = eb2[c];
            #pragma unroll
            for (int ri = 0; ri < 4; ++ri) {
                float d = f32_dist(Cr[ri], ebc, acc[ri][ci]);
                if (d < bestd[ri]) { bestd[ri] = d; besti[ri] = c; }
            }
        }
    }
    __syncthreads();
    #pragma unroll
    for (int ri = 0; ri < 4; ++ri) {
        redd[ty * 4 + ri][tx] = bestd[ri];
        redi[ty * 4 + ri][tx] = besti[ri];
    }
    __syncthreads();
    if (t < 64) {
        float bd = redd[t][0]; int bi = redi[t][0];
        for (int j = 1; j < 16; ++j) {
            float d = redd[t][j]; int i2 = redi[t][j];
            if (d < bd || (d == bd && i2 < bi)) { bd = d; bi = i2; }
        }
        bsel[t] = bi;
        out[1 + (size_t)NROWS * DIM + row0 + t] = (float)bi;
    }
    __syncthreads();
    double lacc = 0.0;
    {
        int r = t >> 2, qd = (t & 3) * 64;
        int bi = bsel[r];
        const float* qrow = e + (size_t)bi * DIM + qd;
        float* orow = out + 1 + (size_t)(row0 + r) * DIM + qd;
        #pragma unroll 4
        for (int d = 0; d < 64; ++d) {
            float qv = qrow[d], zv = zt[r][qd + d];
            double df = (double)qv - (double)zv;
            lacc += df * df;
            orow[d] = qv;
        }
    }
    for (int off = 32; off > 0; off >>= 1) lacc += __shfl_down(lacc, off, 64);
    if ((t & 63) == 0) lred[t >> 6] = lacc;
    __syncthreads();
    if (t == 0) partial[blockIdx.x] = lred[0] + lred[1] + lred[2] + lred[3];
}

// ============================ launch ============================

extern "C" void kernel_launch(void* const* d_in, const int* in_sizes, int n_in,
                              void* d_out, int out_size, void* d_ws, size_t ws_size,
                              hipStream_t stream) {
    const float* z = (const float*)d_in[0];
    const float* e = (const float*)d_in[1];
    float* out = (float*)d_out;
    char* w = (char*)d_ws;

    size_t o = 0;
    auto take = [&](size_t b) { size_t r = o; o = (o + b + 255) & ~(size_t)255; return r; };
    size_t o_zh = take((size_t)NROWS * DIM * 2);
    size_t o_eh = take((size_t)KCODES * DIM * 2);
    size_t o_cr = take((size_t)NROWS * 4);
    size_t o_eb = take((size_t)KCODES * 4);
    size_t o_tk = take((size_t)32 * NROWS * 4);
    size_t o_t2 = take((size_t)32 * NROWS * 4);
    size_t o_fk = take((size_t)NROWS * 8);
    size_t o_cn = take(512);
    size_t o_ls = take((size_t)128 * LCAP * 4);
    size_t o_pt = take((size_t)2048 * 8);
    size_t need = o;

    if (ws_size >= need) {
        ushort* zh = (ushort*)(w + o_zh);
        ushort* eh = (ushort*)(w + o_eh);
        float* Cr  = (float*)(w + o_cr);
        float* eb  = (float*)(w + o_eb);
        float* tk  = (float*)(w + o_tk);
        uint*  tk2 = (uint*)(w + o_t2);
        u64*   fk  = (u64*)(w + o_fk);
        int*   cn  = (int*)(w + o_cn);
        int*   ls  = (int*)(w + o_ls);
        double* pt = (double*)(w + o_pt);

        k_split<<<NROWS * DIM / 8 / 256, 256, 0, stream>>>(z, zh, NROWS * DIM / 8);
        k_split<<<KCODES * DIM / 8 / 256, 256, 0, stream>>>(e, eh, KCODES * DIM / 8);
        k_rownorm<<<NROWS / 256, 256, 0, stream>>>(z, Cr, NROWS);
        k_rownorm<<<KCODES / 256, 256, 0, stream>>>(e, eb, KCODES);
        k_init<<<1, 128, 0, stream>>>(cn);
        k_gemm<<<NROWS / 256, 256, 0, stream>>>(zh, eh, Cr, eb, tk, tk2);
        k_lists<<<NROWS / 256, 256, 0, stream>>>(tk, tk2, cn, ls, fk);
        dim3 ge(128, 16);
        k_exact<<<ge, 256, 0, stream>>>(z, e, Cr, eb, ls, cn, fk);
        k_gather<<<NROWS / 32, 256, 0, stream>>>(z, e, fk, out, pt);
        k_finish<<<1, 256, 0, stream>>>(pt, out, 2048);
    } else {
        float* Cr  = (float*)w;
        float* eb  = Cr + NROWS;
        double* pt = (double*)(eb + KCODES);
        k_rownorm<<<NROWS / 256, 256, 0, stream>>>(z, Cr, NROWS);
        k_rownorm<<<KCODES / 256, 256, 0, stream>>>(e, eb, KCODES);
        k_main_slow<<<NROWS / 64, 256, 0, stream>>>(z, e, Cr, eb, out, pt);
        k_finish<<<1, 256, 0, stream>>>(pt, out, NROWS / 64);
    }
}